// Round 8
// baseline (824.391 us; speedup 1.0000x reference)
//
#include <hip/hip_runtime.h>
#include <math.h>

typedef unsigned short u16;
typedef _Float16 f16;
typedef f16 f16x4 __attribute__((ext_vector_type(4)));
typedef float f32x4 __attribute__((ext_vector_type(4)));

// ============================================================================
// Register-chained design: 1 wave = 1 batch element (16 rows), zero barriers,
// zero LDS. All GEMMs via mfma_f32_16x16x16_f16 in "swapped" layout:
//   output D: n-dim on (lane>>4)*4+i, m-dim on lane&15
// which IS the B-fragment layout (col=lane&15, k=(lane>>4)*4+0..3) of the next
// GEMM -> direct register chaining. Weights pre-packed in fragment order so
// each MFMA's A-frag is one coalesced 8B/lane load.
// f16 everywhere: v_cvt_f16_f32 is RNE (native bf16 cast truncates - round 6).
// ============================================================================

__device__ __forceinline__ float tanh_f(float x) {
  float e = __expf(2.f * x);
  return 1.f - 2.f / (e + 1.f);
}
__device__ __forceinline__ f16x4 cvt4(f32x4 v) {
  f16x4 r;
  r[0] = (f16)v[0]; r[1] = (f16)v[1]; r[2] = (f16)v[2]; r[3] = (f16)v[3];
  return r;
}

// acc[T][n on g*4+i][m on sr] += sum_k W[16T+?][k] * act[m][k]
// a = weight frag (A[n-rows][k]), b = activation frag (B[k][m-cols])
template <int KT>  // KT = K/16
__device__ __forceinline__ void mmchain(const u16* __restrict__ Wf, const f16x4* bfr,
                                        f32x4 acc[16], int lane) {
  const u16* base = Wf + (size_t)lane * 4;
#pragma unroll
  for (int T = 0; T < 16; ++T) {
    f32x4 a = {};
#pragma unroll
    for (int Tk = 0; Tk < KT; ++Tk) {
      f16x4 wf = *(const f16x4*)(base + (size_t)(T * KT + Tk) * 256);
      a = __builtin_amdgcn_mfma_f32_16x16x16f16(wf, bfr[Tk], a, 0, 0, 0);
    }
    acc[T] = a;
  }
}

// swapped: a = activation (A[m-rows][k]), b = weight frag (B[k][n-cols])
// -> D[m on g*4+i][n on sr]   (used for V so PV's A-frag needs no transpose)
template <int KT>
__device__ __forceinline__ void mmchain_sw(const u16* __restrict__ Wf, const f16x4* bfr,
                                           f32x4 acc[16], int lane) {
  const u16* base = Wf + (size_t)lane * 4;
#pragma unroll
  for (int T = 0; T < 16; ++T) {
    f32x4 a = {};
#pragma unroll
    for (int Tk = 0; Tk < KT; ++Tk) {
      f16x4 wf = *(const f16x4*)(base + (size_t)(T * KT + Tk) * 256);
      a = __builtin_amdgcn_mfma_f32_16x16x16f16(bfr[Tk], wf, a, 0, 0, 0);
    }
    acc[T] = a;
  }
}

__global__ __launch_bounds__(256) void fused_kernel(
    const int* __restrict__ x, const float* __restrict__ node_emb,
    const u16* __restrict__ wq, const u16* __restrict__ wk, const u16* __restrict__ wv,
    const u16* __restrict__ wfc1, const u16* __restrict__ w11, const u16* __restrict__ w12,
    const u16* __restrict__ w21, const u16* __restrict__ w22,
    const float* __restrict__ aux,
    const float* __restrict__ p1_b1, const float* __restrict__ p1_b2,
    const float* __restrict__ p1_lng, const float* __restrict__ p1_lnb,
    const float* __restrict__ p2_b1, const float* __restrict__ p2_b2,
    const float* __restrict__ lnc1_g, const float* __restrict__ lnc1_b,
    const float* __restrict__ lnc2_g, const float* __restrict__ lnc2_b,
    const float* __restrict__ Wcls, const float* __restrict__ bcls,
    float* __restrict__ out) {
  const int lane = threadIdx.x & 63;
  const int wid = threadIdx.x >> 6;
  const int sr = lane & 15, g = lane >> 4;
  const int elem = blockIdx.x * 4 + wid;

  const int xi = x[elem * 16 + sr];
  const float npm = (xi != 0) ? 1.f : 0.f;

  // ---- emb gather (f32, exact LN stats) -> f16 frags; row m = sr ----
  f16x4 ebf[8];
  float mu, rs;
  {
    const float4* erow = (const float4*)(node_emb + (size_t)xi * 128 + g * 4);
    float su = 0.f, sq = 0.f;
#pragma unroll
    for (int t = 0; t < 8; ++t) {
      float4 v = erow[t * 4];
      su += v.x + v.y + v.z + v.w;
      sq += v.x * v.x + v.y * v.y + v.z * v.z + v.w * v.w;
      ebf[t][0] = (f16)v.x; ebf[t][1] = (f16)v.y;
      ebf[t][2] = (f16)v.z; ebf[t][3] = (f16)v.w;
    }
    su += __shfl_xor(su, 16); su += __shfl_xor(su, 32);
    sq += __shfl_xor(sq, 16); sq += __shfl_xor(sq, 32);
    mu = su * (1.f / 128.f);
    rs = rsqrtf(sq * (1.f / 128.f) - mu * mu + 1e-5f);
  }

  // ---- Q, K projections (LN folded: gamma-scaled weights + G/B terms) ----
  f16x4 qf[16], kf[16];
  {
    f32x4 acc[16];
    mmchain<8>(wq, ebf, acc, lane);
#pragma unroll
    for (int T = 0; T < 16; ++T) {
      float4 G4 = *(const float4*)(aux + 0 * 512 + T * 16 + g * 4);
      float4 B4 = *(const float4*)(aux + 0 * 512 + 256 + T * 16 + g * 4);
#pragma unroll
      for (int i = 0; i < 4; ++i)
        qf[T][i] = (f16)(rs * (acc[T][i] - mu * ((const float*)&G4)[i]) + ((const float*)&B4)[i]);
    }
    mmchain<8>(wk, ebf, acc, lane);
#pragma unroll
    for (int T = 0; T < 16; ++T) {
      float4 G4 = *(const float4*)(aux + 1 * 512 + T * 16 + g * 4);
      float4 B4 = *(const float4*)(aux + 1 * 512 + 256 + T * 16 + g * 4);
#pragma unroll
      for (int i = 0; i < 4; ++i)
        kf[T][i] = (f16)(rs * (acc[T][i] - mu * ((const float*)&G4)[i]) + ((const float*)&B4)[i]);
    }
  }

  // ---- V with swapped operands: out D[m on g*4+i][dv on sr] = PV A-frag ----
  f16x4 vtf[16];
  {
    f32x4 acc[16];
    mmchain_sw<8>(wv, ebf, acc, lane);
    float mur[4], rsr[4];
#pragma unroll
    for (int i = 0; i < 4; ++i) {
      mur[i] = __shfl(mu, g * 4 + i);
      rsr[i] = __shfl(rs, g * 4 + i);
    }
#pragma unroll
    for (int T = 0; T < 16; ++T) {
      float Gv = aux[2 * 512 + T * 16 + sr];
      float Bv = aux[2 * 512 + 256 + T * 16 + sr];
#pragma unroll
      for (int i = 0; i < 4; ++i)
        vtf[T][i] = (f16)(rsr[i] * (acc[T][i] - mur[i] * Gv) + Bv);
    }
  }

  // ---- attention: scores swapped (l on g*4+i, m on sr), softmax per m ----
  f16x4 pb[8];
#pragma unroll
  for (int h = 0; h < 8; ++h) {
    f32x4 s4 = {};
    s4 = __builtin_amdgcn_mfma_f32_16x16x16f16(kf[2 * h], qf[2 * h], s4, 0, 0, 0);
    s4 = __builtin_amdgcn_mfma_f32_16x16x16f16(kf[2 * h + 1], qf[2 * h + 1], s4, 0, 0, 0);
    float e4[4], mx = -3.0e38f;
#pragma unroll
    for (int i = 0; i < 4; ++i) {
      float v = s4[i] * 0.17677669529663687f;  // 1/sqrt(32)
      if ((g * 4 + i) == sr) v = -3.0e38f;     // diagonal self-exclusion
      e4[i] = v;
      mx = fmaxf(mx, v);
    }
    mx = fmaxf(mx, __shfl_xor(mx, 16));
    mx = fmaxf(mx, __shfl_xor(mx, 32));
    float sm = 0.f;
#pragma unroll
    for (int i = 0; i < 4; ++i) {
      e4[i] = ((g * 4 + i) == sr) ? 0.f : __expf(e4[i] - mx);
      sm += e4[i];
    }
    sm += __shfl_xor(sm, 16);
    sm += __shfl_xor(sm, 32);
    float inv = 1.f / sm;
#pragma unroll
    for (int i = 0; i < 4; ++i) pb[h][i] = (f16)(e4[i] * inv);
  }

  // ---- PV: ctx[dv on g*4+i][m on sr] -> chain-ready frags ----
  f16x4 cf[16];
#pragma unroll
  for (int T = 0; T < 16; ++T) {
    f32x4 c = {};
    c = __builtin_amdgcn_mfma_f32_16x16x16f16(vtf[T], pb[T >> 1], c, 0, 0, 0);
    cf[T] = cvt4(c);
  }

  // ---- dyn_in = (ctx @ Wfc1^T) * npm ----
  f16x4 dinf[16];
  {
    f32x4 acc[16];
    mmchain<16>(wfc1, cf, acc, lane);
#pragma unroll
    for (int T = 0; T < 16; ++T) {
#pragma unroll
      for (int i = 0; i < 4; ++i) acc[T][i] *= npm;
      dinf[T] = cvt4(acc[T]);
    }
  }

  // ---- h1 = tanh(dyn_in @ p1w1^T + b1) ----
  f16x4 h1f[16];
  {
    f32x4 acc[16];
    mmchain<16>(w11, dinf, acc, lane);
#pragma unroll
    for (int T = 0; T < 16; ++T) {
      float4 b = *(const float4*)(p1_b1 + T * 16 + g * 4);
#pragma unroll
      for (int i = 0; i < 4; ++i) h1f[T][i] = (f16)tanh_f(acc[T][i] + ((const float*)&b)[i]);
    }
  }

  // ---- h2 = h1 @ p1w2^T + b2 + dyn_in; LN(p1)*npm; stats for lnc1 ----
  float muD, rsD;
  f16x4 d1f[16];
  {
    f32x4 dacc[16];
    mmchain<16>(w12, h1f, dacc, lane);
    float s1 = 0.f, s2 = 0.f;
#pragma unroll
    for (int T = 0; T < 16; ++T) {
      float4 b = *(const float4*)(p1_b2 + T * 16 + g * 4);
#pragma unroll
      for (int i = 0; i < 4; ++i) {
        float v = dacc[T][i] + ((const float*)&b)[i] + (float)dinf[T][i];
        dacc[T][i] = v;
        s1 += v;
        s2 += v * v;
      }
    }
    s1 += __shfl_xor(s1, 16); s1 += __shfl_xor(s1, 32);
    s2 += __shfl_xor(s2, 16); s2 += __shfl_xor(s2, 32);
    float muA = s1 * (1.f / 256.f);
    float rsA = rsqrtf(s2 * (1.f / 256.f) - muA * muA + 1e-5f);
    float t1 = 0.f, t2 = 0.f;
#pragma unroll
    for (int T = 0; T < 16; ++T) {
      float4 lg = *(const float4*)(p1_lng + T * 16 + g * 4);
      float4 lb = *(const float4*)(p1_lnb + T * 16 + g * 4);
#pragma unroll
      for (int i = 0; i < 4; ++i) {
        float v = ((dacc[T][i] - muA) * rsA * ((const float*)&lg)[i] + ((const float*)&lb)[i]) * npm;
        dacc[T][i] = v;
        t1 += v;
        t2 += v * v;
      }
    }
    t1 += __shfl_xor(t1, 16); t1 += __shfl_xor(t1, 32);
    t2 += __shfl_xor(t2, 16); t2 += __shfl_xor(t2, 32);
    muD = t1 * (1.f / 256.f);
    rsD = rsqrtf(t2 * (1.f / 256.f) - muD * muD + 1e-5f);
#pragma unroll
    for (int T = 0; T < 16; ++T) d1f[T] = cvt4(dacc[T]);  // post-LN ~N(0,1): f16 safe
  }

  // ---- static path: st1 = tanh(npm*(emb @ p2w1^T) + b1); sta = (st1@p2w2^T+b2)*npm ----
  f32x4 sacc[16];
  float muS, rsS;
  {
    f16x4 s1f[16];
    {
      f32x4 acc[16];
      mmchain<8>(w21, ebf, acc, lane);
#pragma unroll
      for (int T = 0; T < 16; ++T) {
        float4 b = *(const float4*)(p2_b1 + T * 16 + g * 4);
#pragma unroll
        for (int i = 0; i < 4; ++i)
          s1f[T][i] = (f16)tanh_f(npm * acc[T][i] + ((const float*)&b)[i]);
      }
    }
    mmchain<16>(w22, s1f, sacc, lane);
    float s1 = 0.f, s2 = 0.f;
#pragma unroll
    for (int T = 0; T < 16; ++T) {
      float4 b = *(const float4*)(p2_b2 + T * 16 + g * 4);
#pragma unroll
      for (int i = 0; i < 4; ++i) {
        float v = (sacc[T][i] + ((const float*)&b)[i]) * npm;
        sacc[T][i] = v;
        s1 += v;
        s2 += v * v;
      }
    }
    s1 += __shfl_xor(s1, 16); s1 += __shfl_xor(s1, 32);
    s2 += __shfl_xor(s2, 16); s2 += __shfl_xor(s2, 32);
    muS = s1 * (1.f / 256.f);
    rsS = rsqrtf(s2 * (1.f / 256.f) - muS * muS + 1e-5f);
  }

  // ---- classifier: (LN(dyn,c1) - LN(sta,c2))^2 @ Wcls, sigmoid, masked mean ----
  {
    float pp = 0.f;
#pragma unroll
    for (int T = 0; T < 16; ++T) {
      float4 c1g = *(const float4*)(lnc1_g + T * 16 + g * 4);
      float4 c1b = *(const float4*)(lnc1_b + T * 16 + g * 4);
      float4 c2g = *(const float4*)(lnc2_g + T * 16 + g * 4);
      float4 c2b = *(const float4*)(lnc2_b + T * 16 + g * 4);
      float4 wc = *(const float4*)(Wcls + T * 16 + g * 4);
#pragma unroll
      for (int i = 0; i < 4; ++i) {
        float dn = ((float)d1f[T][i] - muD) * rsD * ((const float*)&c1g)[i] + ((const float*)&c1b)[i];
        float st = (sacc[T][i] - muS) * rsS * ((const float*)&c2g)[i] + ((const float*)&c2b)[i];
        float df = dn - st;
        pp = fmaf(df * df, ((const float*)&wc)[i], pp);
      }
    }
    pp += __shfl_xor(pp, 16);
    pp += __shfl_xor(pp, 32);
    float logit = pp + bcls[0];
    float prob = npm / (1.f + __expf(-logit));
    float ns = npm;
#pragma unroll
    for (int o = 1; o < 16; o <<= 1) {
      prob += __shfl_xor(prob, o);
      ns += __shfl_xor(ns, o);
    }
    if (lane == 0) out[elem] = prob / ns;
  }
}

// ---- prep: fp32 weights -> f16 FRAGMENT-PACKED (qkv gamma-scaled) + aux ----
// frag layout: u16 idx = blk*256 + ((k>>2)&3)*64 + (n&15)*4 + (k&3),
//              blk = (n>>4)*(K>>4) + (k>>4)
__global__ void prep_all(const float* __restrict__ Wq, const float* __restrict__ Wk,
                         const float* __restrict__ Wv, const float* __restrict__ Wfc1,
                         const float* __restrict__ p1w1, const float* __restrict__ p1w2,
                         const float* __restrict__ p2w1, const float* __restrict__ p2w2,
                         const float* __restrict__ g1, const float* __restrict__ b1,
                         const float* __restrict__ g2, const float* __restrict__ b2,
                         const float* __restrict__ g3, const float* __restrict__ b3,
                         u16* __restrict__ ws, float* __restrict__ aux) {
  int bx = blockIdx.x, t = threadIdx.x;
  if (bx >= 1536) {
    int m = bx - 1536;
    const float* W = (m == 0) ? Wq : (m == 1) ? Wk : Wv;
    const float* gg = (m == 0) ? g1 : (m == 1) ? g2 : g3;
    const float* bb = (m == 0) ? b1 : (m == 1) ? b2 : b3;
    float G = 0.f, Bv = 0.f;
    for (int k = 0; k < 128; ++k) {
      float w = W[t * 128 + k];
      G += w * gg[k];
      Bv += w * bb[k];
    }
    aux[m * 512 + t] = G;
    aux[m * 512 + 256 + t] = Bv;
    return;
  }
  const float* src;
  u16* dst;
  const float* sc = nullptr;
  int base, K;
  if (bx < 128) {
    src = Wq; dst = ws; sc = g1; base = bx; K = 128;
  } else if (bx < 256) {
    src = Wk; dst = ws + 32768; sc = g2; base = bx - 128; K = 128;
  } else if (bx < 384) {
    src = Wv; dst = ws + 65536; sc = g3; base = bx - 256; K = 128;
  } else if (bx < 640) {
    src = Wfc1; dst = ws + 98304; base = bx - 384; K = 256;
  } else if (bx < 896) {
    src = p1w1; dst = ws + 163840; base = bx - 640; K = 256;
  } else if (bx < 1152) {
    src = p1w2; dst = ws + 229376; base = bx - 896; K = 256;
  } else if (bx < 1280) {
    src = p2w1; dst = ws + 294912; base = bx - 1152; K = 128;
  } else {
    src = p2w2; dst = ws + 327680; base = bx - 1280; K = 256;
  }
  int i = base * 256 + t;
  int n, k;
  if (K == 128) {
    n = i >> 7; k = i & 127;
  } else {
    n = i >> 8; k = i & 255;
  }
  float v = src[i];
  if (sc) v *= sc[k];
  int blk = (n >> 4) * (K >> 4) + (k >> 4);
  int di = (blk << 8) + (((k >> 2) & 3) << 6) + ((n & 15) << 2) + (k & 3);
  dst[di] = __builtin_bit_cast(u16, (f16)v);
}

extern "C" void kernel_launch(void* const* d_in, const int* in_sizes, int n_in,
                              void* d_out, int out_size, void* d_ws, size_t ws_size,
                              hipStream_t stream) {
  const int* x = (const int*)d_in[0];
  const float* node_emb = (const float*)d_in[1];
  const float* ln1_g = (const float*)d_in[2];
  const float* ln1_b = (const float*)d_in[3];
  const float* ln2_g = (const float*)d_in[4];
  const float* ln2_b = (const float*)d_in[5];
  const float* ln3_g = (const float*)d_in[6];
  const float* ln3_b = (const float*)d_in[7];
  const float* Wq = (const float*)d_in[8];
  const float* Wk = (const float*)d_in[9];
  const float* Wv = (const float*)d_in[10];
  const float* Wfc1 = (const float*)d_in[11];
  const float* p1_w1 = (const float*)d_in[12];
  const float* p1_b1 = (const float*)d_in[13];
  const float* p1_w2 = (const float*)d_in[14];
  const float* p1_b2 = (const float*)d_in[15];
  const float* p1_lng = (const float*)d_in[16];
  const float* p1_lnb = (const float*)d_in[17];
  const float* p2_w1 = (const float*)d_in[18];
  const float* p2_b1 = (const float*)d_in[19];
  const float* p2_w2 = (const float*)d_in[20];
  const float* p2_b2 = (const float*)d_in[21];
  const float* lnc1_g = (const float*)d_in[22];
  const float* lnc1_b = (const float*)d_in[23];
  const float* lnc2_g = (const float*)d_in[24];
  const float* lnc2_b = (const float*)d_in[25];
  const float* Wcls = (const float*)d_in[26];
  const float* bcls = (const float*)d_in[27];

  u16* ws = (u16*)d_ws;
  float* aux = (float*)(ws + 393216);

  prep_all<<<1539, 256, 0, stream>>>(Wq, Wk, Wv, Wfc1, p1_w1, p1_w2, p2_w1, p2_w2, ln1_g, ln1_b,
                                     ln2_g, ln2_b, ln3_g, ln3_b, ws, aux);

  const int B = in_sizes[0] / 16;
  fused_kernel<<<B / 4, 256, 0, stream>>>(
      x, node_emb, ws, ws + 32768, ws + 65536, ws + 98304, ws + 163840, ws + 229376, ws + 294912,
      ws + 327680, aux, p1_b1, p1_b2, p1_lng, p1_lnb, p2_b1, p2_b2, lnc1_g, lnc1_b, lnc2_g, lnc2_b,
      Wcls, bcls, (float*)d_out);
}

// Round 9
// 433.490 us; speedup vs baseline: 1.9018x; 1.9018x over previous
//
#include <hip/hip_runtime.h>
#include <math.h>

typedef unsigned short u16;
typedef _Float16 f16;
typedef f16 f16x4 __attribute__((ext_vector_type(4)));
typedef f16 f16x8v __attribute__((ext_vector_type(8)));
typedef float f32x4 __attribute__((ext_vector_type(4)));

// ============================================================================
// Hybrid: activations register-chained per wave (1 wave = 1 batch element,
// mfma_f32_16x16x16_f16, D-layout == next B-frag layout), weights cooperatively
// double-buffered through LDS in 16 KB chunks (global_load_lds width=16) and
// shared by the block's 4 waves -> 4x less L2 weight traffic than round 8.
// Weights pre-packed PAIR-INTERLEAVED: one ds_read_b128 = two MFMA A-frags.
// f16 everywhere: v_cvt_f16_f32 is RNE (native bf16 cast truncates - round 6).
// ============================================================================

__device__ __forceinline__ float tanh_f(float x) {
  float e = __expf(2.f * x);
  return 1.f - 2.f / (e + 1.f);
}
__device__ __forceinline__ f16x4 cvt4(f32x4 v) {
  f16x4 r;
  r[0] = (f16)v[0]; r[1] = (f16)v[1]; r[2] = (f16)v[2]; r[3] = (f16)v[3];
  return r;
}

// stage one 16 KB chunk: 4 waves x 4 issues x (64 lanes x 16 B)
__device__ __forceinline__ void stage16k(const u16* __restrict__ src, u16* dst,
                                         int wid, int lane) {
#pragma unroll
  for (int j = 0; j < 4; ++j) {
    int seg = j * 4 + wid;  // 16 segments of 1 KB
    __builtin_amdgcn_global_load_lds(
        (const __attribute__((address_space(1))) void*)(src + seg * 512 + lane * 8),
        (__attribute__((address_space(3))) void*)(dst + seg * 512), 16, 0, 0);
  }
}

// Staged GEMM: acc[T] = sum_k W[T-tile][k] (x) bfr[k-tile]
// KT = K/16. SW=false: weights as A (out n on g*4+i, m on sr).
//            SW=true : weights as B (out m on g*4+i, n on sr).
template <int KT, bool SW>
__device__ __forceinline__ void gemm_staged(const u16* __restrict__ W, const f16x4* bfr,
                                            f32x4 acc[16], u16* wbuf, int wid, int lane) {
  constexpr int PT = KT / 2;     // frag-pairs per T-tile
  constexpr int TCH = 16 / PT;   // T-tiles per 16 KB chunk (KT=16 -> 2, KT=8 -> 4)
  constexpr int CH = 16 / TCH;   // chunks (8 or 4)
  stage16k(W, wbuf, wid, lane);
  __syncthreads();
  for (int c = 0; c < CH; ++c) {
    if (c + 1 < CH) stage16k(W + (c + 1) * 8192, wbuf + ((c + 1) & 1) * 8192, wid, lane);
    const u16* buf = wbuf + (c & 1) * 8192;
#pragma unroll
    for (int t = 0; t < TCH; ++t) {
      f32x4 a = {};
#pragma unroll
      for (int p = 0; p < PT; ++p) {
        f16x8v w = *(const f16x8v*)(buf + (t * PT + p) * 512 + lane * 8);
        f16x4 w0 = __builtin_shufflevector(w, w, 0, 1, 2, 3);
        f16x4 w1 = __builtin_shufflevector(w, w, 4, 5, 6, 7);
        if constexpr (!SW) {
          a = __builtin_amdgcn_mfma_f32_16x16x16f16(w0, bfr[2 * p], a, 0, 0, 0);
          a = __builtin_amdgcn_mfma_f32_16x16x16f16(w1, bfr[2 * p + 1], a, 0, 0, 0);
        } else {
          a = __builtin_amdgcn_mfma_f32_16x16x16f16(bfr[2 * p], w0, a, 0, 0, 0);
          a = __builtin_amdgcn_mfma_f32_16x16x16f16(bfr[2 * p + 1], w1, a, 0, 0, 0);
        }
      }
      acc[c * TCH + t] = a;
    }
    __syncthreads();
  }
}

__global__ __launch_bounds__(256) void fused_kernel(
    const int* __restrict__ x, const float* __restrict__ node_emb,
    const u16* __restrict__ wq, const u16* __restrict__ wk, const u16* __restrict__ wv,
    const u16* __restrict__ wfc1, const u16* __restrict__ w11, const u16* __restrict__ w12,
    const u16* __restrict__ w21, const u16* __restrict__ w22,
    const float* __restrict__ aux,
    const float* __restrict__ p1_b1, const float* __restrict__ p1_b2,
    const float* __restrict__ p1_lng, const float* __restrict__ p1_lnb,
    const float* __restrict__ p2_b1, const float* __restrict__ p2_b2,
    const float* __restrict__ lnc1_g, const float* __restrict__ lnc1_b,
    const float* __restrict__ lnc2_g, const float* __restrict__ lnc2_b,
    const float* __restrict__ Wcls, const float* __restrict__ bcls,
    float* __restrict__ out) {
  __shared__ __align__(16) u16 wbuf[16384];  // 2 x 16 KB chunk buffers
  const int lane = threadIdx.x & 63;
  const int wid = threadIdx.x >> 6;
  const int sr = lane & 15, g = lane >> 4;
  const int elem = blockIdx.x * 4 + wid;

  const int xi = x[elem * 16 + sr];
  const float npm = (xi != 0) ? 1.f : 0.f;

  // ---- emb gather (f32, exact LN stats) -> f16 frags; row m = sr ----
  f16x4 ebf[8];
  float mu, rs;
  {
    const float4* erow = (const float4*)(node_emb + (size_t)xi * 128 + g * 4);
    float su = 0.f, sq = 0.f;
#pragma unroll
    for (int t = 0; t < 8; ++t) {
      float4 v = erow[t * 4];
      su += v.x + v.y + v.z + v.w;
      sq += v.x * v.x + v.y * v.y + v.z * v.z + v.w * v.w;
      ebf[t][0] = (f16)v.x; ebf[t][1] = (f16)v.y;
      ebf[t][2] = (f16)v.z; ebf[t][3] = (f16)v.w;
    }
    su += __shfl_xor(su, 16); su += __shfl_xor(su, 32);
    sq += __shfl_xor(sq, 16); sq += __shfl_xor(sq, 32);
    mu = su * (1.f / 128.f);
    rs = rsqrtf(sq * (1.f / 128.f) - mu * mu + 1e-5f);
  }

  // ---- Q, K projections (LN folded: gamma-scaled weights + G/B terms) ----
  f16x4 qf[16], kf[16];
  {
    f32x4 acc[16];
    gemm_staged<8, false>(wq, ebf, acc, wbuf, wid, lane);
#pragma unroll
    for (int T = 0; T < 16; ++T) {
      float4 G4 = *(const float4*)(aux + 0 * 512 + T * 16 + g * 4);
      float4 B4 = *(const float4*)(aux + 0 * 512 + 256 + T * 16 + g * 4);
#pragma unroll
      for (int i = 0; i < 4; ++i)
        qf[T][i] = (f16)(rs * (acc[T][i] - mu * ((const float*)&G4)[i]) + ((const float*)&B4)[i]);
    }
    gemm_staged<8, false>(wk, ebf, acc, wbuf, wid, lane);
#pragma unroll
    for (int T = 0; T < 16; ++T) {
      float4 G4 = *(const float4*)(aux + 1 * 512 + T * 16 + g * 4);
      float4 B4 = *(const float4*)(aux + 1 * 512 + 256 + T * 16 + g * 4);
#pragma unroll
      for (int i = 0; i < 4; ++i)
        kf[T][i] = (f16)(rs * (acc[T][i] - mu * ((const float*)&G4)[i]) + ((const float*)&B4)[i]);
    }
  }

  // ---- V with swapped operands: out D[m on g*4+i][dv on sr] = PV A-frag ----
  f16x4 vtf[16];
  {
    f32x4 acc[16];
    gemm_staged<8, true>(wv, ebf, acc, wbuf, wid, lane);
    float mur[4], rsr[4];
#pragma unroll
    for (int i = 0; i < 4; ++i) {
      mur[i] = __shfl(mu, g * 4 + i);
      rsr[i] = __shfl(rs, g * 4 + i);
    }
#pragma unroll
    for (int T = 0; T < 16; ++T) {
      float Gv = aux[2 * 512 + T * 16 + sr];
      float Bv = aux[2 * 512 + 256 + T * 16 + sr];
#pragma unroll
      for (int i = 0; i < 4; ++i)
        vtf[T][i] = (f16)(rsr[i] * (acc[T][i] - mur[i] * Gv) + Bv);
    }
  }

  // ---- attention: scores swapped (l on g*4+i, m on sr), softmax per m ----
  f16x4 pb[8];
#pragma unroll
  for (int h = 0; h < 8; ++h) {
    f32x4 s4 = {};
    s4 = __builtin_amdgcn_mfma_f32_16x16x16f16(kf[2 * h], qf[2 * h], s4, 0, 0, 0);
    s4 = __builtin_amdgcn_mfma_f32_16x16x16f16(kf[2 * h + 1], qf[2 * h + 1], s4, 0, 0, 0);
    float e4[4], mx = -3.0e38f;
#pragma unroll
    for (int i = 0; i < 4; ++i) {
      float v = s4[i] * 0.17677669529663687f;  // 1/sqrt(32)
      if ((g * 4 + i) == sr) v = -3.0e38f;     // diagonal self-exclusion
      e4[i] = v;
      mx = fmaxf(mx, v);
    }
    mx = fmaxf(mx, __shfl_xor(mx, 16));
    mx = fmaxf(mx, __shfl_xor(mx, 32));
    float sm = 0.f;
#pragma unroll
    for (int i = 0; i < 4; ++i) {
      e4[i] = ((g * 4 + i) == sr) ? 0.f : __expf(e4[i] - mx);
      sm += e4[i];
    }
    sm += __shfl_xor(sm, 16);
    sm += __shfl_xor(sm, 32);
    float inv = 1.f / sm;
#pragma unroll
    for (int i = 0; i < 4; ++i) pb[h][i] = (f16)(e4[i] * inv);
  }

  // ---- PV: ctx[dv on g*4+i][m on sr] -> chain-ready frags ----
  f16x4 cf[16];
#pragma unroll
  for (int T = 0; T < 16; ++T) {
    f32x4 c = {};
    c = __builtin_amdgcn_mfma_f32_16x16x16f16(vtf[T], pb[T >> 1], c, 0, 0, 0);
    cf[T] = cvt4(c);
  }

  // ---- dyn_in = (ctx @ Wfc1^T) * npm ----
  f16x4 dinf[16];
  {
    f32x4 acc[16];
    gemm_staged<16, false>(wfc1, cf, acc, wbuf, wid, lane);
#pragma unroll
    for (int T = 0; T < 16; ++T) {
#pragma unroll
      for (int i = 0; i < 4; ++i) acc[T][i] *= npm;
      dinf[T] = cvt4(acc[T]);
    }
  }

  // ---- h1 = tanh(dyn_in @ p1w1^T + b1) ----
  f16x4 h1f[16];
  {
    f32x4 acc[16];
    gemm_staged<16, false>(w11, dinf, acc, wbuf, wid, lane);
#pragma unroll
    for (int T = 0; T < 16; ++T) {
      float4 b = *(const float4*)(p1_b1 + T * 16 + g * 4);
#pragma unroll
      for (int i = 0; i < 4; ++i) h1f[T][i] = (f16)tanh_f(acc[T][i] + ((const float*)&b)[i]);
    }
  }

  // ---- h2 = h1 @ p1w2^T + b2 + dyn_in; LN(p1)*npm; stats for lnc1 ----
  float muD, rsD;
  f16x4 d1f[16];
  {
    f32x4 dacc[16];
    gemm_staged<16, false>(w12, h1f, dacc, wbuf, wid, lane);
    float s1 = 0.f, s2 = 0.f;
#pragma unroll
    for (int T = 0; T < 16; ++T) {
      float4 b = *(const float4*)(p1_b2 + T * 16 + g * 4);
#pragma unroll
      for (int i = 0; i < 4; ++i) {
        float v = dacc[T][i] + ((const float*)&b)[i] + (float)dinf[T][i];
        dacc[T][i] = v;
        s1 += v;
        s2 += v * v;
      }
    }
    s1 += __shfl_xor(s1, 16); s1 += __shfl_xor(s1, 32);
    s2 += __shfl_xor(s2, 16); s2 += __shfl_xor(s2, 32);
    float muA = s1 * (1.f / 256.f);
    float rsA = rsqrtf(s2 * (1.f / 256.f) - muA * muA + 1e-5f);
    float t1 = 0.f, t2 = 0.f;
#pragma unroll
    for (int T = 0; T < 16; ++T) {
      float4 lg = *(const float4*)(p1_lng + T * 16 + g * 4);
      float4 lb = *(const float4*)(p1_lnb + T * 16 + g * 4);
#pragma unroll
      for (int i = 0; i < 4; ++i) {
        float v = ((dacc[T][i] - muA) * rsA * ((const float*)&lg)[i] + ((const float*)&lb)[i]) * npm;
        dacc[T][i] = v;
        t1 += v;
        t2 += v * v;
      }
    }
    t1 += __shfl_xor(t1, 16); t1 += __shfl_xor(t1, 32);
    t2 += __shfl_xor(t2, 16); t2 += __shfl_xor(t2, 32);
    muD = t1 * (1.f / 256.f);
    rsD = rsqrtf(t2 * (1.f / 256.f) - muD * muD + 1e-5f);
#pragma unroll
    for (int T = 0; T < 16; ++T) d1f[T] = cvt4(dacc[T]);  // post-LN ~N(0,1): f16 safe
  }

  // ---- static path: st1 = tanh(npm*(emb @ p2w1^T) + b1); sta = (st1@p2w2^T+b2)*npm ----
  f32x4 sacc[16];
  float muS, rsS;
  {
    f16x4 s1f[16];
    {
      f32x4 acc[16];
      gemm_staged<8, false>(w21, ebf, acc, wbuf, wid, lane);
#pragma unroll
      for (int T = 0; T < 16; ++T) {
        float4 b = *(const float4*)(p2_b1 + T * 16 + g * 4);
#pragma unroll
        for (int i = 0; i < 4; ++i)
          s1f[T][i] = (f16)tanh_f(npm * acc[T][i] + ((const float*)&b)[i]);
      }
    }
    gemm_staged<16, false>(w22, s1f, sacc, wbuf, wid, lane);
    float s1 = 0.f, s2 = 0.f;
#pragma unroll
    for (int T = 0; T < 16; ++T) {
      float4 b = *(const float4*)(p2_b2 + T * 16 + g * 4);
#pragma unroll
      for (int i = 0; i < 4; ++i) {
        float v = (sacc[T][i] + ((const float*)&b)[i]) * npm;
        sacc[T][i] = v;
        s1 += v;
        s2 += v * v;
      }
    }
    s1 += __shfl_xor(s1, 16); s1 += __shfl_xor(s1, 32);
    s2 += __shfl_xor(s2, 16); s2 += __shfl_xor(s2, 32);
    muS = s1 * (1.f / 256.f);
    rsS = rsqrtf(s2 * (1.f / 256.f) - muS * muS + 1e-5f);
  }

  // ---- classifier: (LN(dyn,c1) - LN(sta,c2))^2 @ Wcls, sigmoid, masked mean ----
  {
    float pp = 0.f;
#pragma unroll
    for (int T = 0; T < 16; ++T) {
      float4 c1g = *(const float4*)(lnc1_g + T * 16 + g * 4);
      float4 c1b = *(const float4*)(lnc1_b + T * 16 + g * 4);
      float4 c2g = *(const float4*)(lnc2_g + T * 16 + g * 4);
      float4 c2b = *(const float4*)(lnc2_b + T * 16 + g * 4);
      float4 wc = *(const float4*)(Wcls + T * 16 + g * 4);
#pragma unroll
      for (int i = 0; i < 4; ++i) {
        float dn = ((float)d1f[T][i] - muD) * rsD * ((const float*)&c1g)[i] + ((const float*)&c1b)[i];
        float st = (sacc[T][i] - muS) * rsS * ((const float*)&c2g)[i] + ((const float*)&c2b)[i];
        float df = dn - st;
        pp = fmaf(df * df, ((const float*)&wc)[i], pp);
      }
    }
    pp += __shfl_xor(pp, 16);
    pp += __shfl_xor(pp, 32);
    float logit = pp + bcls[0];
    float prob = npm / (1.f + __expf(-logit));
    float ns = npm;
#pragma unroll
    for (int o = 1; o < 16; o <<= 1) {
      prob += __shfl_xor(prob, o);
      ns += __shfl_xor(ns, o);
    }
    if (lane == 0) out[elem] = prob / ns;
  }
}

// ---- prep: fp32 weights -> f16 PAIR-INTERLEAVED fragment packing ----
// block blk = (n>>4)*(K>>4) + (k>>4); lane l = ((k>>2)&3)*16 + (n&15)
// u16 idx = (blk>>1)*512 + l*8 + (blk&1)*4 + (k&3)  -> ds_read_b128 = 2 frags
__global__ void prep_all(const float* __restrict__ Wq, const float* __restrict__ Wk,
                         const float* __restrict__ Wv, const float* __restrict__ Wfc1,
                         const float* __restrict__ p1w1, const float* __restrict__ p1w2,
                         const float* __restrict__ p2w1, const float* __restrict__ p2w2,
                         const float* __restrict__ g1, const float* __restrict__ b1,
                         const float* __restrict__ g2, const float* __restrict__ b2,
                         const float* __restrict__ g3, const float* __restrict__ b3,
                         u16* __restrict__ ws, float* __restrict__ aux) {
  int bx = blockIdx.x, t = threadIdx.x;
  if (bx >= 1536) {
    int m = bx - 1536;
    const float* W = (m == 0) ? Wq : (m == 1) ? Wk : Wv;
    const float* gg = (m == 0) ? g1 : (m == 1) ? g2 : g3;
    const float* bb = (m == 0) ? b1 : (m == 1) ? b2 : b3;
    float G = 0.f, Bv = 0.f;
    for (int k = 0; k < 128; ++k) {
      float w = W[t * 128 + k];
      G += w * gg[k];
      Bv += w * bb[k];
    }
    aux[m * 512 + t] = G;
    aux[m * 512 + 256 + t] = Bv;
    return;
  }
  const float* src;
  u16* dst;
  const float* sc = nullptr;
  int base, K;
  if (bx < 128) {
    src = Wq; dst = ws; sc = g1; base = bx; K = 128;
  } else if (bx < 256) {
    src = Wk; dst = ws + 32768; sc = g2; base = bx - 128; K = 128;
  } else if (bx < 384) {
    src = Wv; dst = ws + 65536; sc = g3; base = bx - 256; K = 128;
  } else if (bx < 640) {
    src = Wfc1; dst = ws + 98304; base = bx - 384; K = 256;
  } else if (bx < 896) {
    src = p1w1; dst = ws + 163840; base = bx - 640; K = 256;
  } else if (bx < 1152) {
    src = p1w2; dst = ws + 229376; base = bx - 896; K = 256;
  } else if (bx < 1280) {
    src = p2w1; dst = ws + 294912; base = bx - 1152; K = 128;
  } else {
    src = p2w2; dst = ws + 327680; base = bx - 1280; K = 256;
  }
  int i = base * 256 + t;
  int n, k;
  if (K == 128) {
    n = i >> 7; k = i & 127;
  } else {
    n = i >> 8; k = i & 255;
  }
  float v = src[i];
  if (sc) v *= sc[k];
  int blk = (n >> 4) * (K >> 4) + (k >> 4);
  int l = (((k >> 2) & 3) << 4) + (n & 15);
  int di = ((blk >> 1) << 9) + (l << 3) + ((blk & 1) << 2) + (k & 3);
  dst[di] = __builtin_bit_cast(u16, (f16)v);
}

extern "C" void kernel_launch(void* const* d_in, const int* in_sizes, int n_in,
                              void* d_out, int out_size, void* d_ws, size_t ws_size,
                              hipStream_t stream) {
  const int* x = (const int*)d_in[0];
  const float* node_emb = (const float*)d_in[1];
  const float* ln1_g = (const float*)d_in[2];
  const float* ln1_b = (const float*)d_in[3];
  const float* ln2_g = (const float*)d_in[4];
  const float* ln2_b = (const float*)d_in[5];
  const float* ln3_g = (const float*)d_in[6];
  const float* ln3_b = (const float*)d_in[7];
  const float* Wq = (const float*)d_in[8];
  const float* Wk = (const float*)d_in[9];
  const float* Wv = (const float*)d_in[10];
  const float* Wfc1 = (const float*)d_in[11];
  const float* p1_w1 = (const float*)d_in[12];
  const float* p1_b1 = (const float*)d_in[13];
  const float* p1_w2 = (const float*)d_in[14];
  const float* p1_b2 = (const float*)d_in[15];
  const float* p1_lng = (const float*)d_in[16];
  const float* p1_lnb = (const float*)d_in[17];
  const float* p2_w1 = (const float*)d_in[18];
  const float* p2_b1 = (const float*)d_in[19];
  const float* p2_w2 = (const float*)d_in[20];
  const float* p2_b2 = (const float*)d_in[21];
  const float* lnc1_g = (const float*)d_in[22];
  const float* lnc1_b = (const float*)d_in[23];
  const float* lnc2_g = (const float*)d_in[24];
  const float* lnc2_b = (const float*)d_in[25];
  const float* Wcls = (const float*)d_in[26];
  const float* bcls = (const float*)d_in[27];

  u16* ws = (u16*)d_ws;
  float* aux = (float*)(ws + 393216);

  prep_all<<<1539, 256, 0, stream>>>(Wq, Wk, Wv, Wfc1, p1_w1, p1_w2, p2_w1, p2_w2, ln1_g, ln1_b,
                                     ln2_g, ln2_b, ln3_g, ln3_b, ws, aux);

  const int B = in_sizes[0] / 16;
  fused_kernel<<<B / 4, 256, 0, stream>>>(
      x, node_emb, ws, ws + 32768, ws + 65536, ws + 98304, ws + 163840, ws + 229376, ws + 294912,
      ws + 327680, aux, p1_b1, p1_b2, p1_lng, p1_lnb, p2_b1, p2_b2, lnc1_g, lnc1_b, lnc2_g, lnc2_b,
      Wcls, bcls, (float*)d_out);
}

// Round 10
// 419.236 us; speedup vs baseline: 1.9664x; 1.0340x over previous
//
#include <hip/hip_runtime.h>
#include <math.h>

typedef unsigned short u16;
typedef _Float16 f16;
typedef f16 f16x4 __attribute__((ext_vector_type(4)));
typedef f16 f16x8v __attribute__((ext_vector_type(8)));
typedef float f32x4 __attribute__((ext_vector_type(4)));

// ============================================================================
// Continuous weight-stream pipeline. 1 wave = 1 batch element; activations
// register-chained (mfma_f32_16x16x16_f16, D-layout == next B-frag layout).
// All 8 weight matrices pre-packed (pair-interleaved frag order) into ONE
// 768 KB stream = 96 x 8 KB chunks consumed in fixed order:
//   wq(0-7) wk(8-15) wv(16-23) wfc1(24-39) w11(40-55) w12(56-71)
//   w21(72-79) w22(80-95)
// LDS: 4 x 8KB ring; prefetch depth 2; per chunk: stage(c+2) ->
// s_waitcnt vmcnt(4) (counted, never 0 in loop) -> raw s_barrier -> compute.
// Slot for stage(c+2) was last read at chunk c-2 (two barriers ago) -> one
// barrier per chunk suffices. Per-chunk epilogues keep acc regs tiny.
// f16 everywhere: v_cvt_f16_f32 is RNE (native bf16 cast truncates - round 6).
// ============================================================================

__device__ __forceinline__ float tanh_f(float x) {
  float e = __expf(2.f * x);
  return 1.f - 2.f / (e + 1.f);
}
__device__ __forceinline__ f16x4 cvt4(f32x4 v) {
  f16x4 r;
  r[0] = (f16)v[0]; r[1] = (f16)v[1]; r[2] = (f16)v[2]; r[3] = (f16)v[3];
  return r;
}

// stage one 8KB chunk (source chunk si) into ring slot ds; 2 loads/wave
__device__ __forceinline__ void stage_chunk(const u16* __restrict__ wall, u16* wbuf,
                                            int si, int ds, int wid, int lane) {
  const u16* src = wall + (size_t)si * 4096;
  u16* dst = wbuf + ds * 4096;
#pragma unroll
  for (int j = 0; j < 2; ++j) {
    int seg = wid * 2 + j;  // 8 segments x 1 KB
    __builtin_amdgcn_global_load_lds(
        (const __attribute__((address_space(1))) void*)(src + seg * 512 + lane * 8),
        (__attribute__((address_space(3))) void*)(dst + seg * 512), 16, 0, 0);
  }
}

__device__ __forceinline__ const u16* pipe_acq(const u16* __restrict__ wall, u16* wbuf,
                                               int c, int wid, int lane) {
  int nx = c + 2;
  if (nx >= 96) nx -= 96;  // dummy re-stage at tail (never read; drained at end)
  stage_chunk(wall, wbuf, nx, (c + 2) & 3, wid, lane);
  asm volatile("s_waitcnt vmcnt(4)" ::: "memory");  // chunk c complete; c+1,c+2 in flight
  __builtin_amdgcn_sched_barrier(0);
  __builtin_amdgcn_s_barrier();
  __builtin_amdgcn_sched_barrier(0);
  return wbuf + (c & 3) * 4096;
}

// one 16-col output tile; PT frag-pairs; pair p at buf + (pairbase+p)*512 u16
template <int PT, bool SW>
__device__ __forceinline__ f32x4 tile_mm(const u16* buf, int pairbase, const f16x4* bfr,
                                         int lane) {
  f32x4 a = {};
#pragma unroll
  for (int p = 0; p < PT; ++p) {
    f16x8v w = *(const f16x8v*)(buf + (pairbase + p) * 512 + (size_t)lane * 8);
    f16x4 w0 = __builtin_shufflevector(w, w, 0, 1, 2, 3);
    f16x4 w1 = __builtin_shufflevector(w, w, 4, 5, 6, 7);
    if constexpr (!SW) {
      a = __builtin_amdgcn_mfma_f32_16x16x16f16(w0, bfr[2 * p], a, 0, 0, 0);
      a = __builtin_amdgcn_mfma_f32_16x16x16f16(w1, bfr[2 * p + 1], a, 0, 0, 0);
    } else {
      a = __builtin_amdgcn_mfma_f32_16x16x16f16(bfr[2 * p], w0, a, 0, 0, 0);
      a = __builtin_amdgcn_mfma_f32_16x16x16f16(bfr[2 * p + 1], w1, a, 0, 0, 0);
    }
  }
  return a;
}

__global__ __launch_bounds__(256) void fused_kernel(
    const int* __restrict__ x, const float* __restrict__ node_emb,
    const u16* __restrict__ wall, const float* __restrict__ aux,
    const float* __restrict__ p1_b1, const float* __restrict__ p1_b2,
    const float* __restrict__ p1_lng, const float* __restrict__ p1_lnb,
    const float* __restrict__ p2_b1, const float* __restrict__ p2_b2,
    const float* __restrict__ lnc1_g, const float* __restrict__ lnc1_b,
    const float* __restrict__ lnc2_g, const float* __restrict__ lnc2_b,
    const float* __restrict__ Wcls, const float* __restrict__ bcls,
    float* __restrict__ out) {
  __shared__ __align__(16) u16 wbuf[16384];  // 4 x 8 KB ring
  const int lane = threadIdx.x & 63;
  const int wid = threadIdx.x >> 6;
  const int sr = lane & 15, g = lane >> 4;
  const int elem = blockIdx.x * 4 + wid;

  const int xi = x[elem * 16 + sr];
  const float npm = (xi != 0) ? 1.f : 0.f;

  // prologue stages first: DMA overlaps the emb gather below
  stage_chunk(wall, wbuf, 0, 0, wid, lane);
  stage_chunk(wall, wbuf, 1, 1, wid, lane);

  // ---- emb gather (f32, exact LN stats) -> f16 B-frags; row m = sr ----
  f16x4 ebf[8];
  float mu, rs;
  {
    const float4* erow = (const float4*)(node_emb + (size_t)xi * 128 + g * 4);
    float su = 0.f, sq = 0.f;
#pragma unroll
    for (int t = 0; t < 8; ++t) {
      float4 v = erow[t * 4];
      su += v.x + v.y + v.z + v.w;
      sq += v.x * v.x + v.y * v.y + v.z * v.z + v.w * v.w;
      ebf[t][0] = (f16)v.x; ebf[t][1] = (f16)v.y;
      ebf[t][2] = (f16)v.z; ebf[t][3] = (f16)v.w;
    }
    su += __shfl_xor(su, 16); su += __shfl_xor(su, 32);
    sq += __shfl_xor(sq, 16); sq += __shfl_xor(sq, 32);
    mu = su * (1.f / 128.f);
    rs = rsqrtf(sq * (1.f / 128.f) - mu * mu + 1e-5f);
  }

  int c = 0;

  // ---- wq (chunks 0-7): Q tiles, LN folded via aux G/B ----
  f16x4 qf[16];
#pragma unroll
  for (int cc = 0; cc < 8; ++cc) {
    const u16* buf = pipe_acq(wall, wbuf, c, wid, lane);
#pragma unroll
    for (int t = 0; t < 2; ++t) {
      f32x4 a = tile_mm<4, false>(buf, t * 4, ebf, lane);
      const int T = cc * 2 + t;
      float4 G4 = *(const float4*)(aux + T * 16 + g * 4);
      float4 B4 = *(const float4*)(aux + 256 + T * 16 + g * 4);
#pragma unroll
      for (int i = 0; i < 4; ++i)
        qf[T][i] = (f16)(rs * (a[i] - mu * ((const float*)&G4)[i]) + ((const float*)&B4)[i]);
    }
    ++c;
  }

  // ---- wk (8-15): K tiles -> per-chunk head scores + softmax -> pb[head] ----
  f16x4 pb[8];
#pragma unroll
  for (int cc = 0; cc < 8; ++cc) {
    const u16* buf = pipe_acq(wall, wbuf, c, wid, lane);
    f16x4 kt[2];
#pragma unroll
    for (int t = 0; t < 2; ++t) {
      f32x4 a = tile_mm<4, false>(buf, t * 4, ebf, lane);
      const int T = cc * 2 + t;
      float4 G4 = *(const float4*)(aux + 512 + T * 16 + g * 4);
      float4 B4 = *(const float4*)(aux + 512 + 256 + T * 16 + g * 4);
#pragma unroll
      for (int i = 0; i < 4; ++i)
        kt[t][i] = (f16)(rs * (a[i] - mu * ((const float*)&G4)[i]) + ((const float*)&B4)[i]);
    }
    f32x4 s4 = {};
    s4 = __builtin_amdgcn_mfma_f32_16x16x16f16(kt[0], qf[2 * cc], s4, 0, 0, 0);
    s4 = __builtin_amdgcn_mfma_f32_16x16x16f16(kt[1], qf[2 * cc + 1], s4, 0, 0, 0);
    float e4[4], mx = -3.0e38f;
#pragma unroll
    for (int i = 0; i < 4; ++i) {
      float v = s4[i] * 0.17677669529663687f;  // 1/sqrt(32)
      if ((g * 4 + i) == sr) v = -3.0e38f;     // diagonal self-exclusion
      e4[i] = v;
      mx = fmaxf(mx, v);
    }
    mx = fmaxf(mx, __shfl_xor(mx, 16));
    mx = fmaxf(mx, __shfl_xor(mx, 32));
    float sm = 0.f;
#pragma unroll
    for (int i = 0; i < 4; ++i) {
      e4[i] = ((g * 4 + i) == sr) ? 0.f : __expf(e4[i] - mx);
      sm += e4[i];
    }
    sm += __shfl_xor(sm, 16);
    sm += __shfl_xor(sm, 32);
    float inv = 1.f / sm;
#pragma unroll
    for (int i = 0; i < 4; ++i) pb[cc][i] = (f16)(e4[i] * inv);
    ++c;
  }

  // ---- wv (16-23, swapped): V tile -> immediate PV -> cf tiles ----
  f16x4 cf[16];
  {
    float mur[4], rsr[4];
#pragma unroll
    for (int i = 0; i < 4; ++i) {
      mur[i] = __shfl(mu, g * 4 + i);
      rsr[i] = __shfl(rs, g * 4 + i);
    }
#pragma unroll
    for (int cc = 0; cc < 8; ++cc) {
      const u16* buf = pipe_acq(wall, wbuf, c, wid, lane);
#pragma unroll
      for (int t = 0; t < 2; ++t) {
        f32x4 a = tile_mm<4, true>(buf, t * 4, ebf, lane);
        const int T = cc * 2 + t;
        float Gv = aux[1024 + T * 16 + sr];
        float Bv = aux[1024 + 256 + T * 16 + sr];
        f16x4 vt;
#pragma unroll
        for (int i = 0; i < 4; ++i) vt[i] = (f16)(rsr[i] * (a[i] - mur[i] * Gv) + Bv);
        f32x4 cacc = {};
        cacc = __builtin_amdgcn_mfma_f32_16x16x16f16(vt, pb[T >> 1], cacc, 0, 0, 0);
        cf[T] = cvt4(cacc);
      }
      ++c;
    }
  }

  // ---- wfc1 (24-39): dyn_in = (ctx @ Wfc1^T)*npm ----
  f16x4 dinf[16];
#pragma unroll
  for (int T = 0; T < 16; ++T) {
    const u16* buf = pipe_acq(wall, wbuf, c, wid, lane);
    f32x4 a = tile_mm<8, false>(buf, 0, cf, lane);
#pragma unroll
    for (int i = 0; i < 4; ++i) a[i] *= npm;
    dinf[T] = cvt4(a);
    ++c;
  }

  // ---- w11 (40-55): h1 = tanh(din @ p1w1^T + b1) ----
  f16x4 h1f[16];
#pragma unroll
  for (int T = 0; T < 16; ++T) {
    const u16* buf = pipe_acq(wall, wbuf, c, wid, lane);
    f32x4 a = tile_mm<8, false>(buf, 0, dinf, lane);
    float4 b = *(const float4*)(p1_b1 + T * 16 + g * 4);
#pragma unroll
    for (int i = 0; i < 4; ++i) h1f[T][i] = (f16)tanh_f(a[i] + ((const float*)&b)[i]);
    ++c;
  }

  // ---- w12 (56-71): pre-LN h2 = gemm + b2 + dyn_in; f16 store + f32 stats ----
  f16x4 d1f[16];
  float s1 = 0.f, s2 = 0.f;
#pragma unroll
  for (int T = 0; T < 16; ++T) {
    const u16* buf = pipe_acq(wall, wbuf, c, wid, lane);
    f32x4 a = tile_mm<8, false>(buf, 0, h1f, lane);
    float4 b = *(const float4*)(p1_b2 + T * 16 + g * 4);
#pragma unroll
    for (int i = 0; i < 4; ++i) {
      float v = a[i] + ((const float*)&b)[i] + (float)dinf[T][i];
      s1 += v;
      s2 += v * v;
      d1f[T][i] = (f16)v;
    }
    ++c;
  }

  // ---- w21 (72-79): st1 = tanh(npm*(emb @ p2w1^T) + b1) ----
  f16x4 s1f[16];
#pragma unroll
  for (int cc = 0; cc < 8; ++cc) {
    const u16* buf = pipe_acq(wall, wbuf, c, wid, lane);
#pragma unroll
    for (int t = 0; t < 2; ++t) {
      f32x4 a = tile_mm<4, false>(buf, t * 4, ebf, lane);
      const int T = cc * 2 + t;
      float4 b = *(const float4*)(p2_b1 + T * 16 + g * 4);
#pragma unroll
      for (int i = 0; i < 4; ++i)
        s1f[T][i] = (f16)tanh_f(npm * a[i] + ((const float*)&b)[i]);
    }
    ++c;
  }

  // ---- w22 (80-95): static = (st1 @ p2w2^T + b2)*npm; f16 store + f32 stats ----
  f16x4 s16[16];
  float u1 = 0.f, u2 = 0.f;
#pragma unroll
  for (int T = 0; T < 16; ++T) {
    const u16* buf = pipe_acq(wall, wbuf, c, wid, lane);
    f32x4 a = tile_mm<8, false>(buf, 0, s1f, lane);
    float4 b = *(const float4*)(p2_b2 + T * 16 + g * 4);
#pragma unroll
    for (int i = 0; i < 4; ++i) {
      float v = (a[i] + ((const float*)&b)[i]) * npm;
      u1 += v;
      u2 += v * v;
      s16[T][i] = (f16)v;
    }
    ++c;
  }
  asm volatile("s_waitcnt vmcnt(0)" ::: "memory");  // drain tail dummy stages

  // ---- stats: LN(p1) params, static LN params ----
  s1 += __shfl_xor(s1, 16); s1 += __shfl_xor(s1, 32);
  s2 += __shfl_xor(s2, 16); s2 += __shfl_xor(s2, 32);
  const float muA = s1 * (1.f / 256.f);
  const float rsA = rsqrtf(s2 * (1.f / 256.f) - muA * muA + 1e-5f);
  u1 += __shfl_xor(u1, 16); u1 += __shfl_xor(u1, 32);
  u2 += __shfl_xor(u2, 16); u2 += __shfl_xor(u2, 32);
  const float muS = u1 * (1.f / 256.f);
  const float rsS = rsqrtf(u2 * (1.f / 256.f) - muS * muS + 1e-5f);

  // ---- dynamic = LN(p1)(h2)*npm : stats pass (recompute from d1f) ----
  float t1 = 0.f, t2 = 0.f;
#pragma unroll
  for (int T = 0; T < 16; ++T) {
    float4 lg = *(const float4*)(p1_lng + T * 16 + g * 4);
    float4 lb = *(const float4*)(p1_lnb + T * 16 + g * 4);
#pragma unroll
    for (int i = 0; i < 4; ++i) {
      float v = (((float)d1f[T][i] - muA) * rsA * ((const float*)&lg)[i] +
                 ((const float*)&lb)[i]) * npm;
      t1 += v;
      t2 += v * v;
    }
  }
  t1 += __shfl_xor(t1, 16); t1 += __shfl_xor(t1, 32);
  t2 += __shfl_xor(t2, 16); t2 += __shfl_xor(t2, 32);
  const float muD = t1 * (1.f / 256.f);
  const float rsD = rsqrtf(t2 * (1.f / 256.f) - muD * muD + 1e-5f);

  // ---- classifier: (LN(dyn,c1) - LN(sta,c2))^2 @ Wcls, sigmoid, masked mean ----
  {
    float pp = 0.f;
#pragma unroll
    for (int T = 0; T < 16; ++T) {
      float4 lg = *(const float4*)(p1_lng + T * 16 + g * 4);
      float4 lb = *(const float4*)(p1_lnb + T * 16 + g * 4);
      float4 c1g = *(const float4*)(lnc1_g + T * 16 + g * 4);
      float4 c1b = *(const float4*)(lnc1_b + T * 16 + g * 4);
      float4 c2g = *(const float4*)(lnc2_g + T * 16 + g * 4);
      float4 c2b = *(const float4*)(lnc2_b + T * 16 + g * 4);
      float4 wc = *(const float4*)(Wcls + T * 16 + g * 4);
#pragma unroll
      for (int i = 0; i < 4; ++i) {
        float dyn = (((float)d1f[T][i] - muA) * rsA * ((const float*)&lg)[i] +
                     ((const float*)&lb)[i]) * npm;
        float dn = (dyn - muD) * rsD * ((const float*)&c1g)[i] + ((const float*)&c1b)[i];
        float st = ((float)s16[T][i] - muS) * rsS * ((const float*)&c2g)[i] +
                   ((const float*)&c2b)[i];
        float df = dn - st;
        pp = fmaf(df * df, ((const float*)&wc)[i], pp);
      }
    }
    pp += __shfl_xor(pp, 16);
    pp += __shfl_xor(pp, 32);
    float logit = pp + bcls[0];
    float prob = npm / (1.f + __expf(-logit));
    float ns = npm;
#pragma unroll
    for (int o = 1; o < 16; o <<= 1) {
      prob += __shfl_xor(prob, o);
      ns += __shfl_xor(ns, o);
    }
    if (lane == 0) out[elem] = prob / ns;
  }
}

// ---- prep: fp32 weights -> f16 PAIR-INTERLEAVED fragment packing (as R9) ----
// block blk = (n>>4)*(K>>4) + (k>>4); lane l = ((k>>2)&3)*16 + (n&15)
// u16 idx = (blk>>1)*512 + l*8 + (blk&1)*4 + (k&3)  -> ds_read_b128 = 2 frags
__global__ void prep_all(const float* __restrict__ Wq, const float* __restrict__ Wk,
                         const float* __restrict__ Wv, const float* __restrict__ Wfc1,
                         const float* __restrict__ p1w1, const float* __restrict__ p1w2,
                         const float* __restrict__ p2w1, const float* __restrict__ p2w2,
                         const float* __restrict__ g1, const float* __restrict__ b1,
                         const float* __restrict__ g2, const float* __restrict__ b2,
                         const float* __restrict__ g3, const float* __restrict__ b3,
                         u16* __restrict__ ws, float* __restrict__ aux) {
  int bx = blockIdx.x, t = threadIdx.x;
  if (bx >= 1536) {
    int m = bx - 1536;
    const float* W = (m == 0) ? Wq : (m == 1) ? Wk : Wv;
    const float* gg = (m == 0) ? g1 : (m == 1) ? g2 : g3;
    const float* bb = (m == 0) ? b1 : (m == 1) ? b2 : b3;
    float G = 0.f, Bv = 0.f;
    for (int k = 0; k < 128; ++k) {
      float w = W[t * 128 + k];
      G += w * gg[k];
      Bv += w * bb[k];
    }
    aux[m * 512 + t] = G;
    aux[m * 512 + 256 + t] = Bv;
    return;
  }
  const float* src;
  u16* dst;
  const float* sc = nullptr;
  int base, K;
  if (bx < 128) {
    src = Wq; dst = ws; sc = g1; base = bx; K = 128;
  } else if (bx < 256) {
    src = Wk; dst = ws + 32768; sc = g2; base = bx - 128; K = 128;
  } else if (bx < 384) {
    src = Wv; dst = ws + 65536; sc = g3; base = bx - 256; K = 128;
  } else if (bx < 640) {
    src = Wfc1; dst = ws + 98304; base = bx - 384; K = 256;
  } else if (bx < 896) {
    src = p1w1; dst = ws + 163840; base = bx - 640; K = 256;
  } else if (bx < 1152) {
    src = p1w2; dst = ws + 229376; base = bx - 896; K = 256;
  } else if (bx < 1280) {
    src = p2w1; dst = ws + 294912; base = bx - 1152; K = 128;
  } else {
    src = p2w2; dst = ws + 327680; base = bx - 1280; K = 256;
  }
  int i = base * 256 + t;
  int n, k;
  if (K == 128) {
    n = i >> 7; k = i & 127;
  } else {
    n = i >> 8; k = i & 255;
  }
  float v = src[i];
  if (sc) v *= sc[k];
  int blk = (n >> 4) * (K >> 4) + (k >> 4);
  int l = (((k >> 2) & 3) << 4) + (n & 15);
  int di = ((blk >> 1) << 9) + (l << 3) + ((blk & 1) << 2) + (k & 3);
  dst[di] = __builtin_bit_cast(u16, (f16)v);
}

extern "C" void kernel_launch(void* const* d_in, const int* in_sizes, int n_in,
                              void* d_out, int out_size, void* d_ws, size_t ws_size,
                              hipStream_t stream) {
  const int* x = (const int*)d_in[0];
  const float* node_emb = (const float*)d_in[1];
  const float* ln1_g = (const float*)d_in[2];
  const float* ln1_b = (const float*)d_in[3];
  const float* ln2_g = (const float*)d_in[4];
  const float* ln2_b = (const float*)d_in[5];
  const float* ln3_g = (const float*)d_in[6];
  const float* ln3_b = (const float*)d_in[7];
  const float* Wq = (const float*)d_in[8];
  const float* Wk = (const float*)d_in[9];
  const float* Wv = (const float*)d_in[10];
  const float* Wfc1 = (const float*)d_in[11];
  const float* p1_w1 = (const float*)d_in[12];
  const float* p1_b1 = (const float*)d_in[13];
  const float* p1_w2 = (const float*)d_in[14];
  const float* p1_b2 = (const float*)d_in[15];
  const float* p1_lng = (const float*)d_in[16];
  const float* p1_lnb = (const float*)d_in[17];
  const float* p2_w1 = (const float*)d_in[18];
  const float* p2_b1 = (const float*)d_in[19];
  const float* p2_w2 = (const float*)d_in[20];
  const float* p2_b2 = (const float*)d_in[21];
  const float* lnc1_g = (const float*)d_in[22];
  const float* lnc1_b = (const float*)d_in[23];
  const float* lnc2_g = (const float*)d_in[24];
  const float* lnc2_b = (const float*)d_in[25];
  const float* Wcls = (const float*)d_in[26];
  const float* bcls = (const float*)d_in[27];

  u16* ws = (u16*)d_ws;
  float* aux = (float*)(ws + 393216);

  prep_all<<<1539, 256, 0, stream>>>(Wq, Wk, Wv, Wfc1, p1_w1, p1_w2, p2_w1, p2_w2, ln1_g, ln1_b,
                                     ln2_g, ln2_b, ln3_g, ln3_b, ws, aux);

  const int B = in_sizes[0] / 16;
  fused_kernel<<<B / 4, 256, 0, stream>>>(
      x, node_emb, ws, aux, p1_b1, p1_b2, p1_lng, p1_lnb, p2_b1, p2_b2, lnc1_g, lnc1_b, lnc2_g,
      lnc2_b, Wcls, bcls, (float*)d_out);
}

// Round 11
// 340.669 us; speedup vs baseline: 2.4199x; 1.2306x over previous
//
#include <hip/hip_runtime.h>
#include <math.h>

typedef unsigned short u16;
typedef _Float16 f16;
typedef f16 f16x4 __attribute__((ext_vector_type(4)));
typedef f16 f16x8v __attribute__((ext_vector_type(8)));
typedef float f32x4 __attribute__((ext_vector_type(4)));

// ============================================================================
// Continuous weight-stream pipeline, 8 elements/block (512 thr, 1 elem/wave).
// Activations register-chained (mfma_f32_16x16x16_f16, D-layout == next
// B-frag layout). All 8 weight matrices pre-packed (pair-interleaved frag
// order) into ONE 768 KB stream = 96 x 8 KB chunks consumed in fixed order:
//   wq(0-7) wk(8-15) wv(16-23) wfc1(24-39) w11(40-55) w12(56-71)
//   w21(72-79) w22(80-95)
// LDS: 4 x 8KB ring; prefetch depth 2; per chunk: stage(c+2) (1 load/wave) ->
// s_waitcnt vmcnt(2) (counted, never 0 in loop) -> raw s_barrier -> compute.
// Slot for stage(c+2) was last read at chunk c-2 (two barriers ago) -> one
// barrier per chunk suffices. vs R10: half the blocks -> half the chunk-stall
// events per CU; 2 waves/SIMD fill each other's dependency bubbles.
// f16 everywhere: v_cvt_f16_f32 is RNE (native bf16 cast truncates - round 6).
// ============================================================================

__device__ __forceinline__ float tanh_f(float x) {
  float e = __expf(2.f * x);
  return 1.f - 2.f / (e + 1.f);
}
__device__ __forceinline__ f16x4 cvt4(f32x4 v) {
  f16x4 r;
  r[0] = (f16)v[0]; r[1] = (f16)v[1]; r[2] = (f16)v[2]; r[3] = (f16)v[3];
  return r;
}

// stage one 8KB chunk (source chunk si) into ring slot ds; 1 load per wave
__device__ __forceinline__ void stage_chunk(const u16* __restrict__ wall, u16* wbuf,
                                            int si, int ds, int wid, int lane) {
  const u16* src = wall + (size_t)si * 4096;
  u16* dst = wbuf + ds * 4096;
  // 8 segments x 1 KB, one per wave
  __builtin_amdgcn_global_load_lds(
      (const __attribute__((address_space(1))) void*)(src + wid * 512 + lane * 8),
      (__attribute__((address_space(3))) void*)(dst + wid * 512), 16, 0, 0);
}

__device__ __forceinline__ const u16* pipe_acq(const u16* __restrict__ wall, u16* wbuf,
                                               int c, int wid, int lane) {
  int nx = c + 2;
  if (nx >= 96) nx -= 96;  // dummy re-stage at tail (never read; drained at end)
  stage_chunk(wall, wbuf, nx, (c + 2) & 3, wid, lane);
  asm volatile("s_waitcnt vmcnt(2)" ::: "memory");  // own chunk-c load complete
  __builtin_amdgcn_sched_barrier(0);
  __builtin_amdgcn_s_barrier();                     // -> ALL waves' c-segments visible
  __builtin_amdgcn_sched_barrier(0);
  return wbuf + (c & 3) * 4096;
}

// one 16-col output tile; PT frag-pairs; pair p at buf + (pairbase+p)*512 u16
template <int PT, bool SW>
__device__ __forceinline__ f32x4 tile_mm(const u16* buf, int pairbase, const f16x4* bfr,
                                         int lane) {
  f32x4 a = {};
#pragma unroll
  for (int p = 0; p < PT; ++p) {
    f16x8v w = *(const f16x8v*)(buf + (pairbase + p) * 512 + (size_t)lane * 8);
    f16x4 w0 = __builtin_shufflevector(w, w, 0, 1, 2, 3);
    f16x4 w1 = __builtin_shufflevector(w, w, 4, 5, 6, 7);
    if constexpr (!SW) {
      a = __builtin_amdgcn_mfma_f32_16x16x16f16(w0, bfr[2 * p], a, 0, 0, 0);
      a = __builtin_amdgcn_mfma_f32_16x16x16f16(w1, bfr[2 * p + 1], a, 0, 0, 0);
    } else {
      a = __builtin_amdgcn_mfma_f32_16x16x16f16(bfr[2 * p], w0, a, 0, 0, 0);
      a = __builtin_amdgcn_mfma_f32_16x16x16f16(bfr[2 * p + 1], w1, a, 0, 0, 0);
    }
  }
  return a;
}

__global__ __launch_bounds__(512) void fused_kernel(
    const int* __restrict__ x, const float* __restrict__ node_emb,
    const u16* __restrict__ wall, const float* __restrict__ aux,
    const float* __restrict__ p1_b1, const float* __restrict__ p1_b2,
    const float* __restrict__ p1_lng, const float* __restrict__ p1_lnb,
    const float* __restrict__ p2_b1, const float* __restrict__ p2_b2,
    const float* __restrict__ lnc1_g, const float* __restrict__ lnc1_b,
    const float* __restrict__ lnc2_g, const float* __restrict__ lnc2_b,
    const float* __restrict__ Wcls, const float* __restrict__ bcls,
    float* __restrict__ out) {
  __shared__ __align__(16) u16 wbuf[16384];  // 4 x 8 KB ring
  const int lane = threadIdx.x & 63;
  const int wid = threadIdx.x >> 6;  // 0..7
  const int sr = lane & 15, g = lane >> 4;
  const int elem = blockIdx.x * 8 + wid;

  const int xi = x[elem * 16 + sr];
  const float npm = (xi != 0) ? 1.f : 0.f;

  // prologue stages first: DMA overlaps the emb gather below
  stage_chunk(wall, wbuf, 0, 0, wid, lane);
  stage_chunk(wall, wbuf, 1, 1, wid, lane);

  // ---- emb gather (f32, exact LN stats) -> f16 B-frags; row m = sr ----
  f16x4 ebf[8];
  float mu, rs;
  {
    const float4* erow = (const float4*)(node_emb + (size_t)xi * 128 + g * 4);
    float su = 0.f, sq = 0.f;
#pragma unroll
    for (int t = 0; t < 8; ++t) {
      float4 v = erow[t * 4];
      su += v.x + v.y + v.z + v.w;
      sq += v.x * v.x + v.y * v.y + v.z * v.z + v.w * v.w;
      ebf[t][0] = (f16)v.x; ebf[t][1] = (f16)v.y;
      ebf[t][2] = (f16)v.z; ebf[t][3] = (f16)v.w;
    }
    su += __shfl_xor(su, 16); su += __shfl_xor(su, 32);
    sq += __shfl_xor(sq, 16); sq += __shfl_xor(sq, 32);
    mu = su * (1.f / 128.f);
    rs = rsqrtf(sq * (1.f / 128.f) - mu * mu + 1e-5f);
  }

  int c = 0;

  // ---- wq (chunks 0-7): Q tiles, LN folded via aux G/B ----
  f16x4 qf[16];
#pragma unroll
  for (int cc = 0; cc < 8; ++cc) {
    const u16* buf = pipe_acq(wall, wbuf, c, wid, lane);
#pragma unroll
    for (int t = 0; t < 2; ++t) {
      f32x4 a = tile_mm<4, false>(buf, t * 4, ebf, lane);
      const int T = cc * 2 + t;
      float4 G4 = *(const float4*)(aux + T * 16 + g * 4);
      float4 B4 = *(const float4*)(aux + 256 + T * 16 + g * 4);
#pragma unroll
      for (int i = 0; i < 4; ++i)
        qf[T][i] = (f16)(rs * (a[i] - mu * ((const float*)&G4)[i]) + ((const float*)&B4)[i]);
    }
    ++c;
  }

  // ---- wk (8-15): K tiles -> per-chunk head scores + softmax -> pb[head] ----
  f16x4 pb[8];
#pragma unroll
  for (int cc = 0; cc < 8; ++cc) {
    const u16* buf = pipe_acq(wall, wbuf, c, wid, lane);
    f16x4 kt[2];
#pragma unroll
    for (int t = 0; t < 2; ++t) {
      f32x4 a = tile_mm<4, false>(buf, t * 4, ebf, lane);
      const int T = cc * 2 + t;
      float4 G4 = *(const float4*)(aux + 512 + T * 16 + g * 4);
      float4 B4 = *(const float4*)(aux + 512 + 256 + T * 16 + g * 4);
#pragma unroll
      for (int i = 0; i < 4; ++i)
        kt[t][i] = (f16)(rs * (a[i] - mu * ((const float*)&G4)[i]) + ((const float*)&B4)[i]);
    }
    f32x4 s4 = {};
    s4 = __builtin_amdgcn_mfma_f32_16x16x16f16(kt[0], qf[2 * cc], s4, 0, 0, 0);
    s4 = __builtin_amdgcn_mfma_f32_16x16x16f16(kt[1], qf[2 * cc + 1], s4, 0, 0, 0);
    float e4[4], mx = -3.0e38f;
#pragma unroll
    for (int i = 0; i < 4; ++i) {
      float v = s4[i] * 0.17677669529663687f;  // 1/sqrt(32)
      if ((g * 4 + i) == sr) v = -3.0e38f;     // diagonal self-exclusion
      e4[i] = v;
      mx = fmaxf(mx, v);
    }
    mx = fmaxf(mx, __shfl_xor(mx, 16));
    mx = fmaxf(mx, __shfl_xor(mx, 32));
    float sm = 0.f;
#pragma unroll
    for (int i = 0; i < 4; ++i) {
      e4[i] = ((g * 4 + i) == sr) ? 0.f : __expf(e4[i] - mx);
      sm += e4[i];
    }
    sm += __shfl_xor(sm, 16);
    sm += __shfl_xor(sm, 32);
    float inv = 1.f / sm;
#pragma unroll
    for (int i = 0; i < 4; ++i) pb[cc][i] = (f16)(e4[i] * inv);
    ++c;
  }

  // ---- wv (16-23, swapped): V tile -> immediate PV -> cf tiles ----
  f16x4 cf[16];
  {
    float mur[4], rsr[4];
#pragma unroll
    for (int i = 0; i < 4; ++i) {
      mur[i] = __shfl(mu, g * 4 + i);
      rsr[i] = __shfl(rs, g * 4 + i);
    }
#pragma unroll
    for (int cc = 0; cc < 8; ++cc) {
      const u16* buf = pipe_acq(wall, wbuf, c, wid, lane);
#pragma unroll
      for (int t = 0; t < 2; ++t) {
        f32x4 a = tile_mm<4, true>(buf, t * 4, ebf, lane);
        const int T = cc * 2 + t;
        float Gv = aux[1024 + T * 16 + sr];
        float Bv = aux[1024 + 256 + T * 16 + sr];
        f16x4 vt;
#pragma unroll
        for (int i = 0; i < 4; ++i) vt[i] = (f16)(rsr[i] * (a[i] - mur[i] * Gv) + Bv);
        f32x4 cacc = {};
        cacc = __builtin_amdgcn_mfma_f32_16x16x16f16(vt, pb[T >> 1], cacc, 0, 0, 0);
        cf[T] = cvt4(cacc);
      }
      ++c;
    }
  }

  // ---- wfc1 (24-39): dyn_in = (ctx @ Wfc1^T)*npm ----
  f16x4 dinf[16];
#pragma unroll
  for (int T = 0; T < 16; ++T) {
    const u16* buf = pipe_acq(wall, wbuf, c, wid, lane);
    f32x4 a = tile_mm<8, false>(buf, 0, cf, lane);
#pragma unroll
    for (int i = 0; i < 4; ++i) a[i] *= npm;
    dinf[T] = cvt4(a);
    ++c;
  }

  // ---- w11 (40-55): h1 = tanh(din @ p1w1^T + b1) ----
  f16x4 h1f[16];
#pragma unroll
  for (int T = 0; T < 16; ++T) {
    const u16* buf = pipe_acq(wall, wbuf, c, wid, lane);
    f32x4 a = tile_mm<8, false>(buf, 0, dinf, lane);
    float4 b = *(const float4*)(p1_b1 + T * 16 + g * 4);
#pragma unroll
    for (int i = 0; i < 4; ++i) h1f[T][i] = (f16)tanh_f(a[i] + ((const float*)&b)[i]);
    ++c;
  }

  // ---- w12 (56-71): pre-LN h2 = gemm + b2 + dyn_in; f16 store + f32 stats ----
  f16x4 d1f[16];
  float s1 = 0.f, s2 = 0.f;
#pragma unroll
  for (int T = 0; T < 16; ++T) {
    const u16* buf = pipe_acq(wall, wbuf, c, wid, lane);
    f32x4 a = tile_mm<8, false>(buf, 0, h1f, lane);
    float4 b = *(const float4*)(p1_b2 + T * 16 + g * 4);
#pragma unroll
    for (int i = 0; i < 4; ++i) {
      float v = a[i] + ((const float*)&b)[i] + (float)dinf[T][i];
      s1 += v;
      s2 += v * v;
      d1f[T][i] = (f16)v;
    }
    ++c;
  }

  // ---- w21 (72-79): st1 = tanh(npm*(emb @ p2w1^T) + b1) ----
  f16x4 s1f[16];
#pragma unroll
  for (int cc = 0; cc < 8; ++cc) {
    const u16* buf = pipe_acq(wall, wbuf, c, wid, lane);
#pragma unroll
    for (int t = 0; t < 2; ++t) {
      f32x4 a = tile_mm<4, false>(buf, t * 4, ebf, lane);
      const int T = cc * 2 + t;
      float4 b = *(const float4*)(p2_b1 + T * 16 + g * 4);
#pragma unroll
      for (int i = 0; i < 4; ++i)
        s1f[T][i] = (f16)tanh_f(npm * a[i] + ((const float*)&b)[i]);
    }
    ++c;
  }

  // ---- w22 (80-95): static = (st1 @ p2w2^T + b2)*npm; f16 store + f32 stats ----
  f16x4 s16[16];
  float u1 = 0.f, u2 = 0.f;
#pragma unroll
  for (int T = 0; T < 16; ++T) {
    const u16* buf = pipe_acq(wall, wbuf, c, wid, lane);
    f32x4 a = tile_mm<8, false>(buf, 0, s1f, lane);
    float4 b = *(const float4*)(p2_b2 + T * 16 + g * 4);
#pragma unroll
    for (int i = 0; i < 4; ++i) {
      float v = (a[i] + ((const float*)&b)[i]) * npm;
      u1 += v;
      u2 += v * v;
      s16[T][i] = (f16)v;
    }
    ++c;
  }
  asm volatile("s_waitcnt vmcnt(0)" ::: "memory");  // drain tail dummy stages

  // ---- stats: LN(p1) params, static LN params ----
  s1 += __shfl_xor(s1, 16); s1 += __shfl_xor(s1, 32);
  s2 += __shfl_xor(s2, 16); s2 += __shfl_xor(s2, 32);
  const float muA = s1 * (1.f / 256.f);
  const float rsA = rsqrtf(s2 * (1.f / 256.f) - muA * muA + 1e-5f);
  u1 += __shfl_xor(u1, 16); u1 += __shfl_xor(u1, 32);
  u2 += __shfl_xor(u2, 16); u2 += __shfl_xor(u2, 32);
  const float muS = u1 * (1.f / 256.f);
  const float rsS = rsqrtf(u2 * (1.f / 256.f) - muS * muS + 1e-5f);

  // ---- dynamic = LN(p1)(h2)*npm : stats pass (recompute from d1f) ----
  float t1 = 0.f, t2 = 0.f;
#pragma unroll
  for (int T = 0; T < 16; ++T) {
    float4 lg = *(const float4*)(p1_lng + T * 16 + g * 4);
    float4 lb = *(const float4*)(p1_lnb + T * 16 + g * 4);
#pragma unroll
    for (int i = 0; i < 4; ++i) {
      float v = (((float)d1f[T][i] - muA) * rsA * ((const float*)&lg)[i] +
                 ((const float*)&lb)[i]) * npm;
      t1 += v;
      t2 += v * v;
    }
  }
  t1 += __shfl_xor(t1, 16); t1 += __shfl_xor(t1, 32);
  t2 += __shfl_xor(t2, 16); t2 += __shfl_xor(t2, 32);
  const float muD = t1 * (1.f / 256.f);
  const float rsD = rsqrtf(t2 * (1.f / 256.f) - muD * muD + 1e-5f);

  // ---- classifier: (LN(dyn,c1) - LN(sta,c2))^2 @ Wcls, sigmoid, masked mean ----
  {
    float pp = 0.f;
#pragma unroll
    for (int T = 0; T < 16; ++T) {
      float4 lg = *(const float4*)(p1_lng + T * 16 + g * 4);
      float4 lb = *(const float4*)(p1_lnb + T * 16 + g * 4);
      float4 c1g = *(const float4*)(lnc1_g + T * 16 + g * 4);
      float4 c1b = *(const float4*)(lnc1_b + T * 16 + g * 4);
      float4 c2g = *(const float4*)(lnc2_g + T * 16 + g * 4);
      float4 c2b = *(const float4*)(lnc2_b + T * 16 + g * 4);
      float4 wc = *(const float4*)(Wcls + T * 16 + g * 4);
#pragma unroll
      for (int i = 0; i < 4; ++i) {
        float dyn = (((float)d1f[T][i] - muA) * rsA * ((const float*)&lg)[i] +
                     ((const float*)&lb)[i]) * npm;
        float dn = (dyn - muD) * rsD * ((const float*)&c1g)[i] + ((const float*)&c1b)[i];
        float st = ((float)s16[T][i] - muS) * rsS * ((const float*)&c2g)[i] +
                   ((const float*)&c2b)[i];
        float df = dn - st;
        pp = fmaf(df * df, ((const float*)&wc)[i], pp);
      }
    }
    pp += __shfl_xor(pp, 16);
    pp += __shfl_xor(pp, 32);
    float logit = pp + bcls[0];
    float prob = npm / (1.f + __expf(-logit));
    float ns = npm;
#pragma unroll
    for (int o = 1; o < 16; o <<= 1) {
      prob += __shfl_xor(prob, o);
      ns += __shfl_xor(ns, o);
    }
    if (lane == 0) out[elem] = prob / ns;
  }
}

// ---- prep: fp32 weights -> f16 PAIR-INTERLEAVED fragment packing (as R9) ----
// block blk = (n>>4)*(K>>4) + (k>>4); lane l = ((k>>2)&3)*16 + (n&15)
// u16 idx = (blk>>1)*512 + l*8 + (blk&1)*4 + (k&3)  -> ds_read_b128 = 2 frags
__global__ void prep_all(const float* __restrict__ Wq, const float* __restrict__ Wk,
                         const float* __restrict__ Wv, const float* __restrict__ Wfc1,
                         const float* __restrict__ p1w1, const float* __restrict__ p1w2,
                         const float* __restrict__ p2w1, const float* __restrict__ p2w2,
                         const float* __restrict__ g1, const float* __restrict__ b1,
                         const float* __restrict__ g2, const float* __restrict__ b2,
                         const float* __restrict__ g3, const float* __restrict__ b3,
                         u16* __restrict__ ws, float* __restrict__ aux) {
  int bx = blockIdx.x, t = threadIdx.x;
  if (bx >= 1536) {
    int m = bx - 1536;
    const float* W = (m == 0) ? Wq : (m == 1) ? Wk : Wv;
    const float* gg = (m == 0) ? g1 : (m == 1) ? g2 : g3;
    const float* bb = (m == 0) ? b1 : (m == 1) ? b2 : b3;
    float G = 0.f, Bv = 0.f;
    for (int k = 0; k < 128; ++k) {
      float w = W[t * 128 + k];
      G += w * gg[k];
      Bv += w * bb[k];
    }
    aux[m * 512 + t] = G;
    aux[m * 512 + 256 + t] = Bv;
    return;
  }
  const float* src;
  u16* dst;
  const float* sc = nullptr;
  int base, K;
  if (bx < 128) {
    src = Wq; dst = ws; sc = g1; base = bx; K = 128;
  } else if (bx < 256) {
    src = Wk; dst = ws + 32768; sc = g2; base = bx - 128; K = 128;
  } else if (bx < 384) {
    src = Wv; dst = ws + 65536; sc = g3; base = bx - 256; K = 128;
  } else if (bx < 640) {
    src = Wfc1; dst = ws + 98304; base = bx - 384; K = 256;
  } else if (bx < 896) {
    src = p1w1; dst = ws + 163840; base = bx - 640; K = 256;
  } else if (bx < 1152) {
    src = p1w2; dst = ws + 229376; base = bx - 896; K = 256;
  } else if (bx < 1280) {
    src = p2w1; dst = ws + 294912; base = bx - 1152; K = 128;
  } else {
    src = p2w2; dst = ws + 327680; base = bx - 1280; K = 256;
  }
  int i = base * 256 + t;
  int n, k;
  if (K == 128) {
    n = i >> 7; k = i & 127;
  } else {
    n = i >> 8; k = i & 255;
  }
  float v = src[i];
  if (sc) v *= sc[k];
  int blk = (n >> 4) * (K >> 4) + (k >> 4);
  int l = (((k >> 2) & 3) << 4) + (n & 15);
  int di = ((blk >> 1) << 9) + (l << 3) + ((blk & 1) << 2) + (k & 3);
  dst[di] = __builtin_bit_cast(u16, (f16)v);
}

extern "C" void kernel_launch(void* const* d_in, const int* in_sizes, int n_in,
                              void* d_out, int out_size, void* d_ws, size_t ws_size,
                              hipStream_t stream) {
  const int* x = (const int*)d_in[0];
  const float* node_emb = (const float*)d_in[1];
  const float* ln1_g = (const float*)d_in[2];
  const float* ln1_b = (const float*)d_in[3];
  const float* ln2_g = (const float*)d_in[4];
  const float* ln2_b = (const float*)d_in[5];
  const float* ln3_g = (const float*)d_in[6];
  const float* ln3_b = (const float*)d_in[7];
  const float* Wq = (const float*)d_in[8];
  const float* Wk = (const float*)d_in[9];
  const float* Wv = (const float*)d_in[10];
  const float* Wfc1 = (const float*)d_in[11];
  const float* p1_w1 = (const float*)d_in[12];
  const float* p1_b1 = (const float*)d_in[13];
  const float* p1_w2 = (const float*)d_in[14];
  const float* p1_b2 = (const float*)d_in[15];
  const float* p1_lng = (const float*)d_in[16];
  const float* p1_lnb = (const float*)d_in[17];
  const float* p2_w1 = (const float*)d_in[18];
  const float* p2_b1 = (const float*)d_in[19];
  const float* p2_w2 = (const float*)d_in[20];
  const float* p2_b2 = (const float*)d_in[21];
  const float* lnc1_g = (const float*)d_in[22];
  const float* lnc1_b = (const float*)d_in[23];
  const float* lnc2_g = (const float*)d_in[24];
  const float* lnc2_b = (const float*)d_in[25];
  const float* Wcls = (const float*)d_in[26];
  const float* bcls = (const float*)d_in[27];

  u16* ws = (u16*)d_ws;
  float* aux = (float*)(ws + 393216);

  prep_all<<<1539, 256, 0, stream>>>(Wq, Wk, Wv, Wfc1, p1_w1, p1_w2, p2_w1, p2_w2, ln1_g, ln1_b,
                                     ln2_g, ln2_b, ln3_g, ln3_b, ws, aux);

  const int B = in_sizes[0] / 16;
  fused_kernel<<<B / 8, 512, 0, stream>>>(
      x, node_emb, ws, aux, p1_b1, p1_b2, p1_lng, p1_lnb, p2_b1, p2_b2, lnc1_g, lnc1_b, lnc2_g,
      lnc2_b, Wcls, bcls, (float*)d_out);
}

// Round 12
// 271.031 us; speedup vs baseline: 3.0417x; 1.2569x over previous
//
#include <hip/hip_runtime.h>
#include <math.h>

typedef unsigned short u16;
typedef _Float16 f16;
typedef f16 f16x4 __attribute__((ext_vector_type(4)));
typedef f16 f16x8v __attribute__((ext_vector_type(8)));
typedef float f32x4 __attribute__((ext_vector_type(4)));

// ============================================================================
// Continuous weight-stream pipeline, 8 elements/block (512 thr, 1 elem/wave).
// Activations register-chained (mfma_f32_16x16x16_f16). 96 x 8 KB chunk
// stream: wq(0-7) wk(8-15) wv(16-23) wfc1(24-39) w11(40-55) w12(56-71)
// w21(72-79) w22(80-95). 4 x 8 KB LDS ring, depth-2 prefetch, counted
// vmcnt(2), one raw s_barrier per chunk.
// R12 change: classifier quadratic form expanded into 9 per-row moment
// accumulators + 6 precomputed column scalars -> s16[] eliminated, d1f[]
// retired progressively in w22 -> peak VGPR under the 128 cap -> no scratch
// spill (R11 had 53 MB spill writes + occupancy throttled to 1 block/CU).
// f16 everywhere: v_cvt_f16_f32 is RNE (native bf16 cast truncates - round 6).
// ============================================================================

__device__ __forceinline__ float tanh_f(float x) {
  float e = __expf(2.f * x);
  return 1.f - 2.f / (e + 1.f);
}
__device__ __forceinline__ f16x4 cvt4(f32x4 v) {
  f16x4 r;
  r[0] = (f16)v[0]; r[1] = (f16)v[1]; r[2] = (f16)v[2]; r[3] = (f16)v[3];
  return r;
}

// stage one 8KB chunk (source chunk si) into ring slot ds; 1 load per wave
__device__ __forceinline__ void stage_chunk(const u16* __restrict__ wall, u16* wbuf,
                                            int si, int ds, int wid, int lane) {
  const u16* src = wall + (size_t)si * 4096;
  u16* dst = wbuf + ds * 4096;
  __builtin_amdgcn_global_load_lds(
      (const __attribute__((address_space(1))) void*)(src + wid * 512 + lane * 8),
      (__attribute__((address_space(3))) void*)(dst + wid * 512), 16, 0, 0);
}

__device__ __forceinline__ const u16* pipe_acq(const u16* __restrict__ wall, u16* wbuf,
                                               int c, int wid, int lane) {
  int nx = c + 2;
  if (nx >= 96) nx -= 96;  // dummy re-stage at tail (never read; drained at end)
  stage_chunk(wall, wbuf, nx, (c + 2) & 3, wid, lane);
  asm volatile("s_waitcnt vmcnt(2)" ::: "memory");  // own chunk-c load complete
  __builtin_amdgcn_sched_barrier(0);
  __builtin_amdgcn_s_barrier();                     // ALL waves' c-segments visible
  __builtin_amdgcn_sched_barrier(0);
  return wbuf + (c & 3) * 4096;
}

// one 16-col output tile; PT frag-pairs; pair p at buf + (pairbase+p)*512 u16
template <int PT, bool SW>
__device__ __forceinline__ f32x4 tile_mm(const u16* buf, int pairbase, const f16x4* bfr,
                                         int lane) {
  f32x4 a = {};
#pragma unroll
  for (int p = 0; p < PT; ++p) {
    f16x8v w = *(const f16x8v*)(buf + (pairbase + p) * 512 + (size_t)lane * 8);
    f16x4 w0 = __builtin_shufflevector(w, w, 0, 1, 2, 3);
    f16x4 w1 = __builtin_shufflevector(w, w, 4, 5, 6, 7);
    if constexpr (!SW) {
      a = __builtin_amdgcn_mfma_f32_16x16x16f16(w0, bfr[2 * p], a, 0, 0, 0);
      a = __builtin_amdgcn_mfma_f32_16x16x16f16(w1, bfr[2 * p + 1], a, 0, 0, 0);
    } else {
      a = __builtin_amdgcn_mfma_f32_16x16x16f16(bfr[2 * p], w0, a, 0, 0, 0);
      a = __builtin_amdgcn_mfma_f32_16x16x16f16(bfr[2 * p + 1], w1, a, 0, 0, 0);
    }
  }
  return a;
}

__global__ __launch_bounds__(512) void fused_kernel(
    const int* __restrict__ x, const float* __restrict__ node_emb,
    const u16* __restrict__ wall, const float* __restrict__ aux,
    const float* __restrict__ p1_b1, const float* __restrict__ p1_b2,
    const float* __restrict__ p1_lng, const float* __restrict__ p1_lnb,
    const float* __restrict__ p2_b1, const float* __restrict__ p2_b2,
    const float* __restrict__ lnc1_g, const float* __restrict__ lnc1_b,
    const float* __restrict__ lnc2_g, const float* __restrict__ lnc2_b,
    const float* __restrict__ Wcls, const float* __restrict__ bcls,
    float* __restrict__ out) {
  __shared__ __align__(16) u16 wbuf[16384];  // 4 x 8 KB ring
  const int lane = threadIdx.x & 63;
  const int wid = threadIdx.x >> 6;  // 0..7
  const int sr = lane & 15, g = lane >> 4;
  const int elem = blockIdx.x * 8 + wid;

  const int xi = x[elem * 16 + sr];
  const float npm = (xi != 0) ? 1.f : 0.f;

  // prologue stages first: DMA overlaps the emb gather below
  stage_chunk(wall, wbuf, 0, 0, wid, lane);
  stage_chunk(wall, wbuf, 1, 1, wid, lane);

  // ---- emb gather (f32, exact LN stats) -> f16 B-frags; row m = sr ----
  f16x4 ebf[8];
  float mu, rs;
  {
    const float4* erow = (const float4*)(node_emb + (size_t)xi * 128 + g * 4);
    float su = 0.f, sq = 0.f;
#pragma unroll
    for (int t = 0; t < 8; ++t) {
      float4 v = erow[t * 4];
      su += v.x + v.y + v.z + v.w;
      sq += v.x * v.x + v.y * v.y + v.z * v.z + v.w * v.w;
      ebf[t][0] = (f16)v.x; ebf[t][1] = (f16)v.y;
      ebf[t][2] = (f16)v.z; ebf[t][3] = (f16)v.w;
    }
    su += __shfl_xor(su, 16); su += __shfl_xor(su, 32);
    sq += __shfl_xor(sq, 16); sq += __shfl_xor(sq, 32);
    mu = su * (1.f / 128.f);
    rs = rsqrtf(sq * (1.f / 128.f) - mu * mu + 1e-5f);
  }

  int c = 0;

  // ---- wq (chunks 0-7): Q tiles, LN folded via aux G/B ----
  f16x4 qf[16];
#pragma unroll
  for (int cc = 0; cc < 8; ++cc) {
    const u16* buf = pipe_acq(wall, wbuf, c, wid, lane);
#pragma unroll
    for (int t = 0; t < 2; ++t) {
      f32x4 a = tile_mm<4, false>(buf, t * 4, ebf, lane);
      const int T = cc * 2 + t;
      float4 G4 = *(const float4*)(aux + T * 16 + g * 4);
      float4 B4 = *(const float4*)(aux + 256 + T * 16 + g * 4);
#pragma unroll
      for (int i = 0; i < 4; ++i)
        qf[T][i] = (f16)(rs * (a[i] - mu * ((const float*)&G4)[i]) + ((const float*)&B4)[i]);
    }
    ++c;
  }

  // ---- wk (8-15): K tiles -> per-chunk head scores + softmax -> pb[head] ----
  f16x4 pb[8];
#pragma unroll
  for (int cc = 0; cc < 8; ++cc) {
    const u16* buf = pipe_acq(wall, wbuf, c, wid, lane);
    f16x4 kt[2];
#pragma unroll
    for (int t = 0; t < 2; ++t) {
      f32x4 a = tile_mm<4, false>(buf, t * 4, ebf, lane);
      const int T = cc * 2 + t;
      float4 G4 = *(const float4*)(aux + 512 + T * 16 + g * 4);
      float4 B4 = *(const float4*)(aux + 512 + 256 + T * 16 + g * 4);
#pragma unroll
      for (int i = 0; i < 4; ++i)
        kt[t][i] = (f16)(rs * (a[i] - mu * ((const float*)&G4)[i]) + ((const float*)&B4)[i]);
    }
    f32x4 s4 = {};
    s4 = __builtin_amdgcn_mfma_f32_16x16x16f16(kt[0], qf[2 * cc], s4, 0, 0, 0);
    s4 = __builtin_amdgcn_mfma_f32_16x16x16f16(kt[1], qf[2 * cc + 1], s4, 0, 0, 0);
    float e4[4], mx = -3.0e38f;
#pragma unroll
    for (int i = 0; i < 4; ++i) {
      float v = s4[i] * 0.17677669529663687f;  // 1/sqrt(32)
      if ((g * 4 + i) == sr) v = -3.0e38f;     // diagonal self-exclusion
      e4[i] = v;
      mx = fmaxf(mx, v);
    }
    mx = fmaxf(mx, __shfl_xor(mx, 16));
    mx = fmaxf(mx, __shfl_xor(mx, 32));
    float sm = 0.f;
#pragma unroll
    for (int i = 0; i < 4; ++i) {
      e4[i] = ((g * 4 + i) == sr) ? 0.f : __expf(e4[i] - mx);
      sm += e4[i];
    }
    sm += __shfl_xor(sm, 16);
    sm += __shfl_xor(sm, 32);
    float inv = 1.f / sm;
#pragma unroll
    for (int i = 0; i < 4; ++i) pb[cc][i] = (f16)(e4[i] * inv);
    ++c;
  }

  // ---- wv (16-23, swapped): V tile -> immediate PV -> cf tiles ----
  f16x4 cf[16];
  {
    float mur[4], rsr[4];
#pragma unroll
    for (int i = 0; i < 4; ++i) {
      mur[i] = __shfl(mu, g * 4 + i);
      rsr[i] = __shfl(rs, g * 4 + i);
    }
#pragma unroll
    for (int cc = 0; cc < 8; ++cc) {
      const u16* buf = pipe_acq(wall, wbuf, c, wid, lane);
#pragma unroll
      for (int t = 0; t < 2; ++t) {
        f32x4 a = tile_mm<4, true>(buf, t * 4, ebf, lane);
        const int T = cc * 2 + t;
        float Gv = aux[1024 + T * 16 + sr];
        float Bv = aux[1024 + 256 + T * 16 + sr];
        f16x4 vt;
#pragma unroll
        for (int i = 0; i < 4; ++i) vt[i] = (f16)(rsr[i] * (a[i] - mur[i] * Gv) + Bv);
        f32x4 cacc = {};
        cacc = __builtin_amdgcn_mfma_f32_16x16x16f16(vt, pb[T >> 1], cacc, 0, 0, 0);
        cf[T] = cvt4(cacc);
      }
      ++c;
    }
  }

  // ---- wfc1 (24-39): dyn_in = (ctx @ Wfc1^T)*npm ----
  f16x4 dinf[16];
#pragma unroll
  for (int T = 0; T < 16; ++T) {
    const u16* buf = pipe_acq(wall, wbuf, c, wid, lane);
    f32x4 a = tile_mm<8, false>(buf, 0, cf, lane);
#pragma unroll
    for (int i = 0; i < 4; ++i) a[i] *= npm;
    dinf[T] = cvt4(a);
    ++c;
  }

  // ---- w11 (40-55): h1 = tanh(din @ p1w1^T + b1) ----
  f16x4 h1f[16];
#pragma unroll
  for (int T = 0; T < 16; ++T) {
    const u16* buf = pipe_acq(wall, wbuf, c, wid, lane);
    f32x4 a = tile_mm<8, false>(buf, 0, dinf, lane);
    float4 b = *(const float4*)(p1_b1 + T * 16 + g * 4);
#pragma unroll
    for (int i = 0; i < 4; ++i) h1f[T][i] = (f16)tanh_f(a[i] + ((const float*)&b)[i]);
    ++c;
  }

  // ---- w12 (56-71): pre-LN h2 = gemm + b2 + dyn_in; f16 store + f32 stats ----
  f16x4 d1f[16];
  float s1 = 0.f, s2 = 0.f;
#pragma unroll
  for (int T = 0; T < 16; ++T) {
    const u16* buf = pipe_acq(wall, wbuf, c, wid, lane);
    f32x4 a = tile_mm<8, false>(buf, 0, h1f, lane);
    float4 b = *(const float4*)(p1_b2 + T * 16 + g * 4);
#pragma unroll
    for (int i = 0; i < 4; ++i) {
      float v = a[i] + ((const float*)&b)[i] + (float)dinf[T][i];
      s1 += v;
      s2 += v * v;
      d1f[T][i] = (f16)v;
    }
    ++c;
  }
  // muA/rsA now (needed inside w22 loop)
  s1 += __shfl_xor(s1, 16); s1 += __shfl_xor(s1, 32);
  s2 += __shfl_xor(s2, 16); s2 += __shfl_xor(s2, 32);
  const float muA = s1 * (1.f / 256.f);
  const float rsA = rsqrtf(s2 * (1.f / 256.f) - muA * muA + 1e-5f);

  // ---- w21 (72-79): st1 = tanh(npm*(emb @ p2w1^T) + b1) ----
  f16x4 s1f[16];
#pragma unroll
  for (int cc = 0; cc < 8; ++cc) {
    const u16* buf = pipe_acq(wall, wbuf, c, wid, lane);
#pragma unroll
    for (int t = 0; t < 2; ++t) {
      f32x4 a = tile_mm<4, false>(buf, t * 4, ebf, lane);
      const int T = cc * 2 + t;
      float4 b = *(const float4*)(p2_b1 + T * 16 + g * 4);
#pragma unroll
      for (int i = 0; i < 4; ++i)
        s1f[T][i] = (f16)tanh_f(npm * a[i] + ((const float*)&b)[i]);
    }
    ++c;
  }

  // ---- w22 (80-95): sta consumed IMMEDIATELY via moment accumulation ----
  // dn-st = a*p*u - b*q*v + w,  w = (e-f) - a*muD*p + b*muS*q
  // logit = sum Wc*(dn-st)^2 expands into 9 per-row moments + 6 const scalars.
  float M_puu = 0.f, M_qvv = 0.f, M_pquv = 0.f;
  float M_pug = 0.f, M_ppu = 0.f, M_pqu = 0.f;
  float M_qvg = 0.f, M_pqv = 0.f, M_qqv = 0.f;
  float t1 = 0.f, t2 = 0.f, v1 = 0.f, v2 = 0.f;
#pragma unroll
  for (int T = 0; T < 16; ++T) {
    const u16* buf = pipe_acq(wall, wbuf, c, wid, lane);
    f32x4 av = tile_mm<8, false>(buf, 0, s1f, lane);
    float4 b2 = *(const float4*)(p2_b2 + T * 16 + g * 4);
    float4 lg = *(const float4*)(p1_lng + T * 16 + g * 4);
    float4 lb = *(const float4*)(p1_lnb + T * 16 + g * 4);
    float4 wc = *(const float4*)(Wcls + T * 16 + g * 4);
    float4 pg4 = *(const float4*)(lnc1_g + T * 16 + g * 4);
    float4 qg4 = *(const float4*)(lnc2_g + T * 16 + g * 4);
    float4 eb4 = *(const float4*)(lnc1_b + T * 16 + g * 4);
    float4 fb4 = *(const float4*)(lnc2_b + T * 16 + g * 4);
#pragma unroll
    for (int i = 0; i < 4; ++i) {
      float v = (av[i] + ((const float*)&b2)[i]) * npm;             // sta
      float u = (((float)d1f[T][i] - muA) * rsA * ((const float*)&lg)[i] +
                 ((const float*)&lb)[i]) * npm;                     // dyn
      t1 += u; t2 += u * u; v1 += v; v2 += v * v;
      float gc = ((const float*)&eb4)[i] - ((const float*)&fb4)[i];
      float pu = ((const float*)&pg4)[i] * u;
      float qv = ((const float*)&qg4)[i] * v;
      float wpu = ((const float*)&wc)[i] * pu;
      float wqv = ((const float*)&wc)[i] * qv;
      M_puu = fmaf(wpu, pu, M_puu);
      M_qvv = fmaf(wqv, qv, M_qvv);
      M_pquv = fmaf(wpu, qv, M_pquv);
      M_pug = fmaf(wpu, gc, M_pug);
      M_ppu = fmaf(wpu, ((const float*)&pg4)[i], M_ppu);
      M_pqu = fmaf(wpu, ((const float*)&qg4)[i], M_pqu);
      M_qvg = fmaf(wqv, gc, M_qvg);
      M_pqv = fmaf(wqv, ((const float*)&pg4)[i], M_pqv);
      M_qqv = fmaf(wqv, ((const float*)&qg4)[i], M_qqv);
    }
    ++c;
  }
  asm volatile("s_waitcnt vmcnt(0)" ::: "memory");  // drain tail dummy stages

  // ---- reduce the 13 per-row accumulators over the 4 g-groups ----
#define RED2(z) z += __shfl_xor(z, 16); z += __shfl_xor(z, 32);
  RED2(t1) RED2(t2) RED2(v1) RED2(v2)
  RED2(M_puu) RED2(M_qvv) RED2(M_pquv)
  RED2(M_pug) RED2(M_ppu) RED2(M_pqu)
  RED2(M_qvg) RED2(M_pqv) RED2(M_qqv)
#undef RED2
  const float muD = t1 * (1.f / 256.f);
  const float aD = rsqrtf(t2 * (1.f / 256.f) - muD * muD + 1e-5f);
  const float muS = v1 * (1.f / 256.f);
  const float bS = rsqrtf(v2 * (1.f / 256.f) - muS * muS + 1e-5f);
  const float* s6 = aux + 1536;  // Mgg, Mpg, Mqg, Mpp, Mqq, Mpq
  float logit = aD * aD * M_puu + bS * bS * M_qvv - 2.f * aD * bS * M_pquv
      + 2.f * aD * (M_pug - aD * muD * M_ppu + bS * muS * M_pqu)
      - 2.f * bS * (M_qvg - aD * muD * M_pqv + bS * muS * M_qqv)
      + s6[0] - 2.f * aD * muD * s6[1] + 2.f * bS * muS * s6[2]
      + aD * aD * muD * muD * s6[3] + bS * bS * muS * muS * s6[4]
      - 2.f * aD * bS * muD * muS * s6[5]
      + bcls[0];
  float prob = npm / (1.f + __expf(-logit));
  float ns = npm;
#pragma unroll
  for (int o = 1; o < 16; o <<= 1) {
    prob += __shfl_xor(prob, o);
    ns += __shfl_xor(ns, o);
  }
  if (lane == 0) out[elem] = prob / ns;
}

// ---- prep: fp32 weights -> f16 PAIR-INTERLEAVED fragment packing (as R9) ----
// block blk = (n>>4)*(K>>4) + (k>>4); lane l = ((k>>2)&3)*16 + (n&15)
// u16 idx = (blk>>1)*512 + l*8 + (blk&1)*4 + (k&3)  -> ds_read_b128 = 2 frags
__global__ void prep_all(const float* __restrict__ Wq, const float* __restrict__ Wk,
                         const float* __restrict__ Wv, const float* __restrict__ Wfc1,
                         const float* __restrict__ p1w1, const float* __restrict__ p1w2,
                         const float* __restrict__ p2w1, const float* __restrict__ p2w2,
                         const float* __restrict__ g1, const float* __restrict__ b1,
                         const float* __restrict__ g2, const float* __restrict__ b2,
                         const float* __restrict__ g3, const float* __restrict__ b3,
                         const float* __restrict__ c1g, const float* __restrict__ c1b,
                         const float* __restrict__ c2g, const float* __restrict__ c2b,
                         const float* __restrict__ Wc,
                         u16* __restrict__ ws, float* __restrict__ aux) {
  int bx = blockIdx.x, t = threadIdx.x;
  if (bx == 1539) {  // classifier constant scalars
    if (t == 0) {
      float mgg = 0.f, mpg = 0.f, mqg = 0.f, mpp = 0.f, mqq = 0.f, mpq = 0.f;
      for (int cx = 0; cx < 256; ++cx) {
        float W = Wc[cx], p = c1g[cx], q = c2g[cx], gg = c1b[cx] - c2b[cx];
        mgg += W * gg * gg; mpg += W * p * gg; mqg += W * q * gg;
        mpp += W * p * p; mqq += W * q * q; mpq += W * p * q;
      }
      aux[1536] = mgg; aux[1537] = mpg; aux[1538] = mqg;
      aux[1539] = mpp; aux[1540] = mqq; aux[1541] = mpq;
    }
    return;
  }
  if (bx >= 1536) {
    int m = bx - 1536;
    const float* W = (m == 0) ? Wq : (m == 1) ? Wk : Wv;
    const float* gg = (m == 0) ? g1 : (m == 1) ? g2 : g3;
    const float* bb = (m == 0) ? b1 : (m == 1) ? b2 : b3;
    float G = 0.f, Bv = 0.f;
    for (int k = 0; k < 128; ++k) {
      float w = W[t * 128 + k];
      G += w * gg[k];
      Bv += w * bb[k];
    }
    aux[m * 512 + t] = G;
    aux[m * 512 + 256 + t] = Bv;
    return;
  }
  const float* src;
  u16* dst;
  const float* sc = nullptr;
  int base, K;
  if (bx < 128) {
    src = Wq; dst = ws; sc = g1; base = bx; K = 128;
  } else if (bx < 256) {
    src = Wk; dst = ws + 32768; sc = g2; base = bx - 128; K = 128;
  } else if (bx < 384) {
    src = Wv; dst = ws + 65536; sc = g3; base = bx - 256; K = 128;
  } else if (bx < 640) {
    src = Wfc1; dst = ws + 98304; base = bx - 384; K = 256;
  } else if (bx < 896) {
    src = p1w1; dst = ws + 163840; base = bx - 640; K = 256;
  } else if (bx < 1152) {
    src = p1w2; dst = ws + 229376; base = bx - 896; K = 256;
  } else if (bx < 1280) {
    src = p2w1; dst = ws + 294912; base = bx - 1152; K = 128;
  } else {
    src = p2w2; dst = ws + 327680; base = bx - 1280; K = 256;
  }
  int i = base * 256 + t;
  int n, k;
  if (K == 128) {
    n = i >> 7; k = i & 127;
  } else {
    n = i >> 8; k = i & 255;
  }
  float v = src[i];
  if (sc) v *= sc[k];
  int blk = (n >> 4) * (K >> 4) + (k >> 4);
  int l = (((k >> 2) & 3) << 4) + (n & 15);
  int di = ((blk >> 1) << 9) + (l << 3) + ((blk & 1) << 2) + (k & 3);
  dst[di] = __builtin_bit_cast(u16, (f16)v);
}

extern "C" void kernel_launch(void* const* d_in, const int* in_sizes, int n_in,
                              void* d_out, int out_size, void* d_ws, size_t ws_size,
                              hipStream_t stream) {
  const int* x = (const int*)d_in[0];
  const float* node_emb = (const float*)d_in[1];
  const float* ln1_g = (const float*)d_in[2];
  const float* ln1_b = (const float*)d_in[3];
  const float* ln2_g = (const float*)d_in[4];
  const float* ln2_b = (const float*)d_in[5];
  const float* ln3_g = (const float*)d_in[6];
  const float* ln3_b = (const float*)d_in[7];
  const float* Wq = (const float*)d_in[8];
  const float* Wk = (const float*)d_in[9];
  const float* Wv = (const float*)d_in[10];
  const float* Wfc1 = (const float*)d_in[11];
  const float* p1_w1 = (const float*)d_in[12];
  const float* p1_b1 = (const float*)d_in[13];
  const float* p1_w2 = (const float*)d_in[14];
  const float* p1_b2 = (const float*)d_in[15];
  const float* p1_lng = (const float*)d_in[16];
  const float* p1_lnb = (const float*)d_in[17];
  const float* p2_w1 = (const float*)d_in[18];
  const float* p2_b1 = (const float*)d_in[19];
  const float* p2_w2 = (const float*)d_in[20];
  const float* p2_b2 = (const float*)d_in[21];
  const float* lnc1_g = (const float*)d_in[22];
  const float* lnc1_b = (const float*)d_in[23];
  const float* lnc2_g = (const float*)d_in[24];
  const float* lnc2_b = (const float*)d_in[25];
  const float* Wcls = (const float*)d_in[26];
  const float* bcls = (const float*)d_in[27];

  u16* ws = (u16*)d_ws;
  float* aux = (float*)(ws + 393216);

  prep_all<<<1540, 256, 0, stream>>>(Wq, Wk, Wv, Wfc1, p1_w1, p1_w2, p2_w1, p2_w2, ln1_g, ln1_b,
                                     ln2_g, ln2_b, ln3_g, ln3_b, lnc1_g, lnc1_b, lnc2_g, lnc2_b,
                                     Wcls, ws, aux);

  const int B = in_sizes[0] / 16;
  fused_kernel<<<B / 8, 512, 0, stream>>>(
      x, node_emb, ws, aux, p1_b1, p1_b2, p1_lng, p1_lnb, p2_b1, p2_b2, lnc1_g, lnc1_b, lnc2_g,
      lnc2_b, Wcls, bcls, (float*)d_out);
}

// Round 13
// 211.056 us; speedup vs baseline: 3.9060x; 1.2842x over previous
//
#include <hip/hip_runtime.h>
#include <math.h>

typedef unsigned short u16;
typedef _Float16 f16;
typedef f16 f16x4 __attribute__((ext_vector_type(4)));
typedef f16 f16x8v __attribute__((ext_vector_type(8)));
typedef float f32x4 __attribute__((ext_vector_type(4)));

// ============================================================================
// R13: same continuous weight-stream pipeline as R12 (8 elems/block, 1
// elem/wave, register-chained activations, moment-expanded classifier) with:
//  (a) K=32 MFMA (mfma_f32_16x16x32_f16). The R12 pair-interleaved packing is
//      already the K=32 fragment layout under a k-permutation shared by both
//      operands (weight lane read = {even-tile g*4+i, odd-tile g*4+i};
//      activation f16x8 = concat of two adjacent K=16 frags) -> big-GEMM MFMA
//      instruction count halves, no repacking, no shuffles.
//  (b) 16 KB chunks: 48 chunks, ring 4 x 16 KB = 64 KB LDS, depth-2 prefetch,
//      counted vmcnt(4), ONE raw s_barrier per chunk -> barrier events halve.
// Stream chunk map (16 KB each): wq 0-3, wk 4-7, wv 8-11, wfc1 12-19,
// w11 20-27, w12 28-35, w21 36-39, w22 40-47.
// f16 everywhere: v_cvt_f16_f32 is RNE (native bf16 cast truncates - round 6).
// ============================================================================

__device__ __forceinline__ float tanh_f(float x) {
  float e = __expf(2.f * x);
  return 1.f - 2.f / (e + 1.f);
}

// stage one 16KB chunk (source chunk si) into ring slot ds; 2 issues per wave
__device__ __forceinline__ void stage_chunk(const u16* __restrict__ wall, u16* wbuf,
                                            int si, int ds, int wid, int lane) {
  const u16* src = wall + (size_t)si * 8192;
  u16* dst = wbuf + ds * 8192;
#pragma unroll
  for (int j = 0; j < 2; ++j) {
    __builtin_amdgcn_global_load_lds(
        (const __attribute__((address_space(1))) void*)(src + j * 4096 + wid * 512 + lane * 8),
        (__attribute__((address_space(3))) void*)(dst + j * 4096 + wid * 512), 16, 0, 0);
  }
}

__device__ __forceinline__ const u16* pipe_acq(const u16* __restrict__ wall, u16* wbuf,
                                               int c, int wid, int lane) {
  int nx = c + 2;
  if (nx >= 48) nx -= 48;  // dummy re-stage at tail (never read; drained at end)
  stage_chunk(wall, wbuf, nx, (c + 2) & 3, wid, lane);
  asm volatile("s_waitcnt vmcnt(4)" ::: "memory");  // own chunk-c loads complete
  __builtin_amdgcn_sched_barrier(0);
  __builtin_amdgcn_s_barrier();                     // ALL waves' c-segments visible
  __builtin_amdgcn_sched_barrier(0);
  return wbuf + (c & 3) * 8192;
}

// one 16-col output tile via K=32 MFMAs; local tile lt, PT = K/32 frags
template <int PT, bool SW>
__device__ __forceinline__ f32x4 tile_mm32(const u16* buf, int lt, const f16x8v* bfr,
                                           int lane) {
  f32x4 a = {};
#pragma unroll
  for (int p = 0; p < PT; ++p) {
    f16x8v w = *(const f16x8v*)(buf + (lt * PT + p) * 512 + (size_t)lane * 8);
    if constexpr (!SW)
      a = __builtin_amdgcn_mfma_f32_16x16x32_f16(w, bfr[p], a, 0, 0, 0);
    else
      a = __builtin_amdgcn_mfma_f32_16x16x32_f16(bfr[p], w, a, 0, 0, 0);
  }
  return a;
}

__global__ __launch_bounds__(512) void fused_kernel(
    const int* __restrict__ x, const float* __restrict__ node_emb,
    const u16* __restrict__ wall, const float* __restrict__ aux,
    const float* __restrict__ p1_b1, const float* __restrict__ p1_b2,
    const float* __restrict__ p1_lng, const float* __restrict__ p1_lnb,
    const float* __restrict__ p2_b1, const float* __restrict__ p2_b2,
    const float* __restrict__ lnc1_g, const float* __restrict__ lnc1_b,
    const float* __restrict__ lnc2_g, const float* __restrict__ lnc2_b,
    const float* __restrict__ Wcls, const float* __restrict__ bcls,
    float* __restrict__ out) {
  __shared__ __align__(16) u16 wbuf[32768];  // 4 x 16 KB ring
  const int lane = threadIdx.x & 63;
  const int wid = threadIdx.x >> 6;  // 0..7
  const int sr = lane & 15, g = lane >> 4;
  const int elem = blockIdx.x * 8 + wid;

  const int xi = x[elem * 16 + sr];
  const float npm = (xi != 0) ? 1.f : 0.f;

  // prologue stages first: DMA overlaps the emb gather below
  stage_chunk(wall, wbuf, 0, 0, wid, lane);
  stage_chunk(wall, wbuf, 1, 1, wid, lane);

  // ---- emb gather (f32, exact LN stats) -> f16 K=32 B-frags; row m = sr ----
  f16x8v ebf8[4];
  float mu, rs;
  {
    const float4* erow = (const float4*)(node_emb + (size_t)xi * 128 + g * 4);
    float su = 0.f, sq = 0.f;
#pragma unroll
    for (int t = 0; t < 8; ++t) {
      float4 v = erow[t * 4];
      su += v.x + v.y + v.z + v.w;
      sq += v.x * v.x + v.y * v.y + v.z * v.z + v.w * v.w;
      const int hb = (t & 1) * 4;
      ebf8[t >> 1][hb + 0] = (f16)v.x;
      ebf8[t >> 1][hb + 1] = (f16)v.y;
      ebf8[t >> 1][hb + 2] = (f16)v.z;
      ebf8[t >> 1][hb + 3] = (f16)v.w;
    }
    su += __shfl_xor(su, 16); su += __shfl_xor(su, 32);
    sq += __shfl_xor(sq, 16); sq += __shfl_xor(sq, 32);
    mu = su * (1.f / 128.f);
    rs = rsqrtf(sq * (1.f / 128.f) - mu * mu + 1e-5f);
  }

  int c = 0;

  // ---- wq (chunks 0-3, 4 tiles each): Q, LN folded via aux G/B ----
  f16x8v qf8[8];
#pragma unroll
  for (int cc = 0; cc < 4; ++cc) {
    const u16* buf = pipe_acq(wall, wbuf, c, wid, lane);
#pragma unroll
    for (int lt = 0; lt < 4; ++lt) {
      f32x4 a = tile_mm32<4, false>(buf, lt, ebf8, lane);
      const int T = cc * 4 + lt;
      float4 G4 = *(const float4*)(aux + T * 16 + g * 4);
      float4 B4 = *(const float4*)(aux + 256 + T * 16 + g * 4);
      const int hb = (T & 1) * 4;
#pragma unroll
      for (int i = 0; i < 4; ++i)
        qf8[T >> 1][hb + i] =
            (f16)(rs * (a[i] - mu * ((const float*)&G4)[i]) + ((const float*)&B4)[i]);
    }
    ++c;
  }

  // ---- wk (4-7): K tiles -> per-head K=32 score MFMA + softmax -> pb[h] ----
  f16x4 pb[8];
#pragma unroll
  for (int cc = 0; cc < 4; ++cc) {
    const u16* buf = pipe_acq(wall, wbuf, c, wid, lane);
#pragma unroll
    for (int hh = 0; hh < 2; ++hh) {
      f16x8v kt8;
#pragma unroll
      for (int sub = 0; sub < 2; ++sub) {
        f32x4 a = tile_mm32<4, false>(buf, hh * 2 + sub, ebf8, lane);
        const int T = cc * 4 + hh * 2 + sub;
        float4 G4 = *(const float4*)(aux + 512 + T * 16 + g * 4);
        float4 B4 = *(const float4*)(aux + 512 + 256 + T * 16 + g * 4);
#pragma unroll
        for (int i = 0; i < 4; ++i)
          kt8[sub * 4 + i] =
              (f16)(rs * (a[i] - mu * ((const float*)&G4)[i]) + ((const float*)&B4)[i]);
      }
      const int h = cc * 2 + hh;
      f32x4 s4 = {};
      s4 = __builtin_amdgcn_mfma_f32_16x16x32_f16(kt8, qf8[h], s4, 0, 0, 0);
      float e4[4], mx = -3.0e38f;
#pragma unroll
      for (int i = 0; i < 4; ++i) {
        float v = s4[i] * 0.17677669529663687f;  // 1/sqrt(32)
        if ((g * 4 + i) == sr) v = -3.0e38f;     // diagonal self-exclusion
        e4[i] = v;
        mx = fmaxf(mx, v);
      }
      mx = fmaxf(mx, __shfl_xor(mx, 16));
      mx = fmaxf(mx, __shfl_xor(mx, 32));
      float sm = 0.f;
#pragma unroll
      for (int i = 0; i < 4; ++i) {
        e4[i] = ((g * 4 + i) == sr) ? 0.f : __expf(e4[i] - mx);
        sm += e4[i];
      }
      sm += __shfl_xor(sm, 16);
      sm += __shfl_xor(sm, 32);
      float inv = 1.f / sm;
#pragma unroll
      for (int i = 0; i < 4; ++i) pb[h][i] = (f16)(e4[i] * inv);
    }
    ++c;
  }

  // ---- wv (8-11, swapped): V tile -> immediate PV (K=16) -> cf8 ----
  f16x8v cf8[8];
  {
    float mur[4], rsr[4];
#pragma unroll
    for (int i = 0; i < 4; ++i) {
      mur[i] = __shfl(mu, g * 4 + i);
      rsr[i] = __shfl(rs, g * 4 + i);
    }
#pragma unroll
    for (int cc = 0; cc < 4; ++cc) {
      const u16* buf = pipe_acq(wall, wbuf, c, wid, lane);
#pragma unroll
      for (int lt = 0; lt < 4; ++lt) {
        f32x4 a = tile_mm32<4, true>(buf, lt, ebf8, lane);
        const int T = cc * 4 + lt;
        float Gv = aux[1024 + T * 16 + sr];
        float Bv = aux[1024 + 256 + T * 16 + sr];
        f16x4 vt;
#pragma unroll
        for (int i = 0; i < 4; ++i) vt[i] = (f16)(rsr[i] * (a[i] - mur[i] * Gv) + Bv);
        f32x4 cacc = {};
        cacc = __builtin_amdgcn_mfma_f32_16x16x16f16(vt, pb[T >> 1], cacc, 0, 0, 0);
        const int hb = (T & 1) * 4;
#pragma unroll
        for (int i = 0; i < 4; ++i) cf8[T >> 1][hb + i] = (f16)cacc[i];
      }
      ++c;
    }
  }

  // ---- wfc1 (12-19, 2 tiles each): dyn_in = (ctx @ Wfc1^T)*npm ----
  f16x8v dinf8[8];
#pragma unroll
  for (int cc = 0; cc < 8; ++cc) {
    const u16* buf = pipe_acq(wall, wbuf, c, wid, lane);
#pragma unroll
    for (int lt = 0; lt < 2; ++lt) {
      f32x4 a = tile_mm32<8, false>(buf, lt, cf8, lane);
      const int T = cc * 2 + lt;
      const int hb = (T & 1) * 4;
#pragma unroll
      for (int i = 0; i < 4; ++i) dinf8[T >> 1][hb + i] = (f16)(a[i] * npm);
    }
    ++c;
  }

  // ---- w11 (20-27): h1 = tanh(din @ p1w1^T + b1) ----
  f16x8v h1f8[8];
#pragma unroll
  for (int cc = 0; cc < 8; ++cc) {
    const u16* buf = pipe_acq(wall, wbuf, c, wid, lane);
#pragma unroll
    for (int lt = 0; lt < 2; ++lt) {
      f32x4 a = tile_mm32<8, false>(buf, lt, dinf8, lane);
      const int T = cc * 2 + lt;
      float4 b = *(const float4*)(p1_b1 + T * 16 + g * 4);
      const int hb = (T & 1) * 4;
#pragma unroll
      for (int i = 0; i < 4; ++i)
        h1f8[T >> 1][hb + i] = (f16)tanh_f(a[i] + ((const float*)&b)[i]);
    }
    ++c;
  }

  // ---- w12 (28-35): pre-LN h2 = gemm + b2 + dyn_in; f16 store + f32 stats ----
  f16x4 d1f[16];
  float s1 = 0.f, s2 = 0.f;
#pragma unroll
  for (int cc = 0; cc < 8; ++cc) {
    const u16* buf = pipe_acq(wall, wbuf, c, wid, lane);
#pragma unroll
    for (int lt = 0; lt < 2; ++lt) {
      f32x4 a = tile_mm32<8, false>(buf, lt, h1f8, lane);
      const int T = cc * 2 + lt;
      float4 b = *(const float4*)(p1_b2 + T * 16 + g * 4);
      const int hb = (T & 1) * 4;
#pragma unroll
      for (int i = 0; i < 4; ++i) {
        float v = a[i] + ((const float*)&b)[i] + (float)dinf8[T >> 1][hb + i];
        s1 += v;
        s2 += v * v;
        d1f[T][i] = (f16)v;
      }
    }
    ++c;
  }
  // muA/rsA now (needed inside w22 loop)
  s1 += __shfl_xor(s1, 16); s1 += __shfl_xor(s1, 32);
  s2 += __shfl_xor(s2, 16); s2 += __shfl_xor(s2, 32);
  const float muA = s1 * (1.f / 256.f);
  const float rsA = rsqrtf(s2 * (1.f / 256.f) - muA * muA + 1e-5f);

  // ---- w21 (36-39): st1 = tanh(npm*(emb @ p2w1^T) + b1) ----
  f16x8v s1f8[8];
#pragma unroll
  for (int cc = 0; cc < 4; ++cc) {
    const u16* buf = pipe_acq(wall, wbuf, c, wid, lane);
#pragma unroll
    for (int lt = 0; lt < 4; ++lt) {
      f32x4 a = tile_mm32<4, false>(buf, lt, ebf8, lane);
      const int T = cc * 4 + lt;
      float4 b = *(const float4*)(p2_b1 + T * 16 + g * 4);
      const int hb = (T & 1) * 4;
#pragma unroll
      for (int i = 0; i < 4; ++i)
        s1f8[T >> 1][hb + i] = (f16)tanh_f(npm * a[i] + ((const float*)&b)[i]);
    }
    ++c;
  }

  // ---- w22 (40-47): sta consumed IMMEDIATELY via moment accumulation ----
  float M_puu = 0.f, M_qvv = 0.f, M_pquv = 0.f;
  float M_pug = 0.f, M_ppu = 0.f, M_pqu = 0.f;
  float M_qvg = 0.f, M_pqv = 0.f, M_qqv = 0.f;
  float t1 = 0.f, t2 = 0.f, v1 = 0.f, v2 = 0.f;
#pragma unroll
  for (int cc = 0; cc < 8; ++cc) {
    const u16* buf = pipe_acq(wall, wbuf, c, wid, lane);
#pragma unroll
    for (int lt = 0; lt < 2; ++lt) {
      f32x4 av = tile_mm32<8, false>(buf, lt, s1f8, lane);
      const int T = cc * 2 + lt;
      float4 b2 = *(const float4*)(p2_b2 + T * 16 + g * 4);
      float4 lg = *(const float4*)(p1_lng + T * 16 + g * 4);
      float4 lb = *(const float4*)(p1_lnb + T * 16 + g * 4);
      float4 wc = *(const float4*)(Wcls + T * 16 + g * 4);
      float4 pg4 = *(const float4*)(lnc1_g + T * 16 + g * 4);
      float4 qg4 = *(const float4*)(lnc2_g + T * 16 + g * 4);
      float4 eb4 = *(const float4*)(lnc1_b + T * 16 + g * 4);
      float4 fb4 = *(const float4*)(lnc2_b + T * 16 + g * 4);
#pragma unroll
      for (int i = 0; i < 4; ++i) {
        float v = (av[i] + ((const float*)&b2)[i]) * npm;             // sta
        float u = (((float)d1f[T][i] - muA) * rsA * ((const float*)&lg)[i] +
                   ((const float*)&lb)[i]) * npm;                     // dyn
        t1 += u; t2 += u * u; v1 += v; v2 += v * v;
        float gc = ((const float*)&eb4)[i] - ((const float*)&fb4)[i];
        float pu = ((const float*)&pg4)[i] * u;
        float qv = ((const float*)&qg4)[i] * v;
        float wpu = ((const float*)&wc)[i] * pu;
        float wqv = ((const float*)&wc)[i] * qv;
        M_puu = fmaf(wpu, pu, M_puu);
        M_qvv = fmaf(wqv, qv, M_qvv);
        M_pquv = fmaf(wpu, qv, M_pquv);
        M_pug = fmaf(wpu, gc, M_pug);
        M_ppu = fmaf(wpu, ((const float*)&pg4)[i], M_ppu);
        M_pqu = fmaf(wpu, ((const float*)&qg4)[i], M_pqu);
        M_qvg = fmaf(wqv, gc, M_qvg);
        M_pqv = fmaf(wqv, ((const float*)&pg4)[i], M_pqv);
        M_qqv = fmaf(wqv, ((const float*)&qg4)[i], M_qqv);
      }
    }
    ++c;
  }
  asm volatile("s_waitcnt vmcnt(0)" ::: "memory");  // drain tail dummy stages

  // ---- reduce the 13 per-row accumulators over the 4 g-groups ----
#define RED2(z) z += __shfl_xor(z, 16); z += __shfl_xor(z, 32);
  RED2(t1) RED2(t2) RED2(v1) RED2(v2)
  RED2(M_puu) RED2(M_qvv) RED2(M_pquv)
  RED2(M_pug) RED2(M_ppu) RED2(M_pqu)
  RED2(M_qvg) RED2(M_pqv) RED2(M_qqv)
#undef RED2
  const float muD = t1 * (1.f / 256.f);
  const float aD = rsqrtf(t2 * (1.f / 256.f) - muD * muD + 1e-5f);
  const float muS = v1 * (1.f / 256.f);
  const float bS = rsqrtf(v2 * (1.f / 256.f) - muS * muS + 1e-5f);
  const float* s6 = aux + 1536;  // Mgg, Mpg, Mqg, Mpp, Mqq, Mpq
  float logit = aD * aD * M_puu + bS * bS * M_qvv - 2.f * aD * bS * M_pquv
      + 2.f * aD * (M_pug - aD * muD * M_ppu + bS * muS * M_pqu)
      - 2.f * bS * (M_qvg - aD * muD * M_pqv + bS * muS * M_qqv)
      + s6[0] - 2.f * aD * muD * s6[1] + 2.f * bS * muS * s6[2]
      + aD * aD * muD * muD * s6[3] + bS * bS * muS * muS * s6[4]
      - 2.f * aD * bS * muD * muS * s6[5]
      + bcls[0];
  float prob = npm / (1.f + __expf(-logit));
  float ns = npm;
#pragma unroll
  for (int o = 1; o < 16; o <<= 1) {
    prob += __shfl_xor(prob, o);
    ns += __shfl_xor(ns, o);
  }
  if (lane == 0) out[elem] = prob / ns;
}

// ---- prep: fp32 weights -> f16 PAIR-INTERLEAVED fragment packing (as R12) ----
// block blk = (n>>4)*(K>>4) + (k>>4); lane l = ((k>>2)&3)*16 + (n&15)
// u16 idx = (blk>>1)*512 + l*8 + (blk&1)*4 + (k&3)
// (pairs of adjacent k-16-tiles = one K=32 fragment per 16B lane read)
__global__ void prep_all(const float* __restrict__ Wq, const float* __restrict__ Wk,
                         const float* __restrict__ Wv, const float* __restrict__ Wfc1,
                         const float* __restrict__ p1w1, const float* __restrict__ p1w2,
                         const float* __restrict__ p2w1, const float* __restrict__ p2w2,
                         const float* __restrict__ g1, const float* __restrict__ b1,
                         const float* __restrict__ g2, const float* __restrict__ b2,
                         const float* __restrict__ g3, const float* __restrict__ b3,
                         const float* __restrict__ c1g, const float* __restrict__ c1b,
                         const float* __restrict__ c2g, const float* __restrict__ c2b,
                         const float* __restrict__ Wc,
                         u16* __restrict__ ws, float* __restrict__ aux) {
  int bx = blockIdx.x, t = threadIdx.x;
  if (bx == 1539) {  // classifier constant scalars
    if (t == 0) {
      float mgg = 0.f, mpg = 0.f, mqg = 0.f, mpp = 0.f, mqq = 0.f, mpq = 0.f;
      for (int cx = 0; cx < 256; ++cx) {
        float W = Wc[cx], p = c1g[cx], q = c2g[cx], gg = c1b[cx] - c2b[cx];
        mgg += W * gg * gg; mpg += W * p * gg; mqg += W * q * gg;
        mpp += W * p * p; mqq += W * q * q; mpq += W * p * q;
      }
      aux[1536] = mgg; aux[1537] = mpg; aux[1538] = mqg;
      aux[1539] = mpp; aux[1540] = mqq; aux[1541] = mpq;
    }
    return;
  }
  if (bx >= 1536) {
    int m = bx - 1536;
    const float* W = (m == 0) ? Wq : (m == 1) ? Wk : Wv;
    const float* gg = (m == 0) ? g1 : (m == 1) ? g2 : g3;
    const float* bb = (m == 0) ? b1 : (m == 1) ? b2 : b3;
    float G = 0.f, Bv = 0.f;
    for (int k = 0; k < 128; ++k) {
      float w = W[t * 128 + k];
      G += w * gg[k];
      Bv += w * bb[k];
    }
    aux[m * 512 + t] = G;
    aux[m * 512 + 256 + t] = Bv;
    return;
  }
  const float* src;
  u16* dst;
  const float* sc = nullptr;
  int base, K;
  if (bx < 128) {
    src = Wq; dst = ws; sc = g1; base = bx; K = 128;
  } else if (bx < 256) {
    src = Wk; dst = ws + 32768; sc = g2; base = bx - 128; K = 128;
  } else if (bx < 384) {
    src = Wv; dst = ws + 65536; sc = g3; base = bx - 256; K = 128;
  } else if (bx < 640) {
    src = Wfc1; dst = ws + 98304; base = bx - 384; K = 256;
  } else if (bx < 896) {
    src = p1w1; dst = ws + 163840; base = bx - 640; K = 256;
  } else if (bx < 1152) {
    src = p1w2; dst = ws + 229376; base = bx - 896; K = 256;
  } else if (bx < 1280) {
    src = p2w1; dst = ws + 294912; base = bx - 1152; K = 128;
  } else {
    src = p2w2; dst = ws + 327680; base = bx - 1280; K = 256;
  }
  int i = base * 256 + t;
  int n, k;
  if (K == 128) {
    n = i >> 7; k = i & 127;
  } else {
    n = i >> 8; k = i & 255;
  }
  float v = src[i];
  if (sc) v *= sc[k];
  int blk = (n >> 4) * (K >> 4) + (k >> 4);
  int l = (((k >> 2) & 3) << 4) + (n & 15);
  int di = ((blk >> 1) << 9) + (l << 3) + ((blk & 1) << 2) + (k & 3);
  dst[di] = __builtin_bit_cast(u16, (f16)v);
}

extern "C" void kernel_launch(void* const* d_in, const int* in_sizes, int n_in,
                              void* d_out, int out_size, void* d_ws, size_t ws_size,
                              hipStream_t stream) {
  const int* x = (const int*)d_in[0];
  const float* node_emb = (const float*)d_in[1];
  const float* ln1_g = (const float*)d_in[2];
  const float* ln1_b = (const float*)d_in[3];
  const float* ln2_g = (const float*)d_in[4];
  const float* ln2_b = (const float*)d_in[5];
  const float* ln3_g = (const float*)d_in[6];
  const float* ln3_b = (const float*)d_in[7];
  const float* Wq = (const float*)d_in[8];
  const float* Wk = (const float*)d_in[9];
  const float* Wv = (const float*)d_in[10];
  const float* Wfc1 = (const float*)d_in[11];
  const float* p1_w1 = (const float*)d_in[12];
  const float* p1_b1 = (const float*)d_in[13];
  const float* p1_w2 = (const float*)d_in[14];
  const float* p1_b2 = (const float*)d_in[15];
  const float* p1_lng = (const float*)d_in[16];
  const float* p1_lnb = (const float*)d_in[17];
  const float* p2_w1 = (const float*)d_in[18];
  const float* p2_b1 = (const float*)d_in[19];
  const float* p2_w2 = (const float*)d_in[20];
  const float* p2_b2 = (const float*)d_in[21];
  const float* lnc1_g = (const float*)d_in[22];
  const float* lnc1_b = (const float*)d_in[23];
  const float* lnc2_g = (const float*)d_in[24];
  const float* lnc2_b = (const float*)d_in[25];
  const float* Wcls = (const float*)d_in[26];
  const float* bcls = (const float*)d_in[27];

  u16* ws = (u16*)d_ws;
  float* aux = (float*)(ws + 393216);

  prep_all<<<1540, 256, 0, stream>>>(Wq, Wk, Wv, Wfc1, p1_w1, p1_w2, p2_w1, p2_w2, ln1_g, ln1_b,
                                     ln2_g, ln2_b, ln3_g, ln3_b, lnc1_g, lnc1_b, lnc2_g, lnc2_b,
                                     Wcls, ws, aux);

  const int B = in_sizes[0] / 16;
  fused_kernel<<<B / 8, 512, 0, stream>>>(
      x, node_emb, ws, aux, p1_b1, p1_b2, p1_lng, p1_lnb, p2_b1, p2_b2, lnc1_g, lnc1_b, lnc2_g,
      lnc2_b, Wcls, bcls, (float*)d_out);
}